// Round 9
// baseline (391.291 us; speedup 1.0000x reference)
//
#include <hip/hip_runtime.h>
#include <hip/hip_bf16.h>
#include <math.h>

#define NE 80000
#define NN 10000
#define NG 16
#define MP_NORM 0.31622776601683794f   // 1/sqrt(10)
#define RBF_NORM 0.60302268915552724f  // sqrt(2/5.5)

// monomial tables: index -> (lx,ly,lz), l
__constant__ int c_mx[20] = {0, 1,0,0, 2,1,1,0,0,0, 3,2,2,1,1,1,0,0,0,0};
__constant__ int c_my[20] = {0, 0,1,0, 0,1,0,2,1,0, 0,1,0,2,1,0,3,2,1,0};
__constant__ int c_mz[20] = {0, 0,0,1, 0,0,1,0,1,2, 0,0,1,0,1,2,0,1,2,3};

__device__ __forceinline__ int l_of_a(int a) {
    return (a >= 10) ? 3 : ((a >= 4) ? 2 : ((a >= 1) ? 1 : 0));
}

// symmetrize one node's 1080-vector (in LDS) -> 324 outputs (LDS or global row)
__device__ __forceinline__ void symm_from_lds(const float* Als, float* brow,
                                              int lane) {
    if (lane >= 54) return;
    const int s2 = lane / 9, c = lane - s2 * 9;
    const float* a = Als + s2 * 180 + c;
    float v[20];
    #pragma unroll
    for (int i = 0; i < 20; i++) v[i] = a[i * 9];
    const float o0 = v[0];
    const float o1 = v[1]*v[1] + v[2]*v[2] + v[3]*v[3];
    const float o2 = v[4]*v[4] + 2.f*v[5]*v[5] + 2.f*v[6]*v[6]
                   + v[7]*v[7] + 2.f*v[8]*v[8] + v[9]*v[9];
    const float o3 = v[10]*v[10] + 3.f*v[11]*v[11] + 3.f*v[12]*v[12]
                   + 3.f*v[13]*v[13] + 6.f*v[14]*v[14] + 3.f*v[15]*v[15]
                   + v[16]*v[16] + 3.f*v[17]*v[17] + 3.f*v[18]*v[18] + v[19]*v[19];
    const float o4 = v[1]*v[1]*v[4] + 2.f*v[1]*v[2]*v[5] + 2.f*v[1]*v[3]*v[6]
                   + 2.f*v[2]*v[1]*v[5] + v[2]*v[2]*v[7] + 2.f*v[2]*v[3]*v[8]
                   + 2.f*v[3]*v[1]*v[6] + 2.f*v[3]*v[2]*v[8] + v[3]*v[3]*v[9];
    const float o5 =
        v[1]*(v[4]*v[10] + 3.f*v[5]*v[11] + 3.f*v[6]*v[12] + 3.f*v[7]*v[13]
              + 6.f*v[8]*v[14] + 3.f*v[9]*v[15])
      + v[2]*(3.f*v[4]*v[11] + 3.f*v[5]*v[13] + 6.f*v[6]*v[14] + v[7]*v[16]
              + 3.f*v[8]*v[17] + 3.f*v[9]*v[18])
      + v[3]*(3.f*v[4]*v[12] + 6.f*v[5]*v[14] + 3.f*v[6]*v[15] + 3.f*v[7]*v[17]
              + 3.f*v[8]*v[18] + v[9]*v[19]);
    float* b = brow + s2 * 54 + c;
    b[0]  = o0;
    b[9]  = o1;
    b[18] = o2;
    b[27] = o3;
    b[36] = o4;
    b[45] = o5;
}

// ---------------------------------------------------------------------------
// CSR build: histogram of dst over fc-active edges, scan, fill.
// ---------------------------------------------------------------------------
__global__ __launch_bounds__(256) void k_hist(
    const float* __restrict__ pos, const int* __restrict__ src,
    const int* __restrict__ dst, const float* __restrict__ shifts,
    int* __restrict__ indeg)
{
    const int e = blockIdx.x * 256 + threadIdx.x;
    if (e >= NE) return;
    const int sn = src[e], dn = dst[e];
    const float vx = pos[3*dn+0] - pos[3*sn+0] + shifts[3*e+0];
    const float vy = pos[3*dn+1] - pos[3*sn+1] + shifts[3*e+1];
    const float vz = pos[3*dn+2] - pos[3*sn+2] + shifts[3*e+2];
    const float r = sqrtf(vx*vx + vy*vy + vz*vz) + 1e-9f;
    if (r * (1.0f / 5.5f) < 1.0f) atomicAdd(&indeg[dn], 1);
}

__global__ __launch_bounds__(256) void k_scan(const int* __restrict__ indeg,
                                              int* __restrict__ offs)
{
    __shared__ int part[256];
    const int t = threadIdx.x;
    int s = 0;
    for (int i = t * 40; i < t * 40 + 40; i++)
        if (i < NN) s += indeg[i];
    part[t] = s;
    __syncthreads();
    if (t == 0) {
        int run = 0;
        for (int i = 0; i < 256; i++) { int v = part[i]; part[i] = run; run += v; }
    }
    __syncthreads();
    int run = part[t];
    for (int i = t * 40; i < t * 40 + 40; i++) {
        if (i < NN) { offs[i] = run; run += indeg[i]; }
    }
}

__global__ __launch_bounds__(256) void k_fill(
    const float* __restrict__ pos, const int* __restrict__ src,
    const int* __restrict__ dst, const float* __restrict__ shifts,
    const int* __restrict__ offs, int* __restrict__ cursor,
    int* __restrict__ elist)
{
    const int e = blockIdx.x * 256 + threadIdx.x;
    if (e >= NE) return;
    const int sn = src[e], dn = dst[e];
    const float vx = pos[3*dn+0] - pos[3*sn+0] + shifts[3*e+0];
    const float vy = pos[3*dn+1] - pos[3*sn+1] + shifts[3*e+1];
    const float vz = pos[3*dn+2] - pos[3*sn+2] + shifts[3*e+2];
    const float r = sqrtf(vx*vx + vy*vy + vz*vz) + 1e-9f;
    if (r * (1.0f / 5.5f) < 1.0f) {
        const int p = offs[dn] + atomicAdd(&cursor[dn], 1);
        elist[p] = e;
    }
}

// ---------------------------------------------------------------------------
// Pass 1, gather form: one wave per node. Accumulate A[n] in registers,
// symmetrize -> Bls (LDS) -> Bf (global), then fused per-node GEMV:
// P1[n][o] = sum_q Bls[q] * W1[2q][o]   (lane = o, coalesced W1 reads)
// ---------------------------------------------------------------------------
__global__ __launch_bounds__(64) void k_node1(
    const float* __restrict__ pos, const int* __restrict__ ntype,
    const int* __restrict__ srcArr, const float* __restrict__ shifts,
    const float* __restrict__ Wemb, const float* __restrict__ freqs,
    const float* __restrict__ W_rt, const int* __restrict__ offs,
    const int* __restrict__ indeg, const int* __restrict__ elist,
    const float* __restrict__ W1,
    float* __restrict__ A, float* __restrict__ Bf, float* __restrict__ P1)
{
    __shared__ float eS[80];     // ang[0..19], code[20..28], radt[29..52]
    __shared__ float Als[1080];
    __shared__ float Bls[324];
    const int n = blockIdx.x, lane = threadIdx.x;
    int ridx[17], aidx[17], cidx[17];
    float acc[17];
    #pragma unroll
    for (int k = 0; k < 17; k++) {
        acc[k] = 0.f;
        const int i = lane + 64 * k;
        const int ii = (i < 1080) ? i : 0;
        const int s2 = ii / 180, rem = ii - s2 * 180;
        const int a = rem / 9, c = rem - a * 9;
        ridx[k] = 29 + l_of_a(a) * 6 + s2; aidx[k] = a; cidx[k] = 20 + c;
    }
    const float px = pos[3*n], py = pos[3*n+1], pz = pos[3*n+2];
    const float ed0 = Wemb[3*ntype[n]], ed1 = Wemb[3*ntype[n]+1],
                ed2 = Wemb[3*ntype[n]+2];
    float fr[6];
    #pragma unroll
    for (int q = 0; q < 6; q++) fr[q] = freqs[q];
    float wrt[6];
    if (lane >= 32 && lane < 56) {
        const int j = lane - 32, l = j / 6, s2 = j % 6;
        #pragma unroll
        for (int q = 0; q < 6; q++) wrt[q] = W_rt[(l*6 + q)*6 + s2];
    }
    const int e0 = offs[n], cnt = indeg[n];
    int e_n = 0, sn_n = 0, tn_n = 0;
    float pnx = 0, pny = 0, pnz = 0, snx = 0, sny = 0, snz = 0;
    if (cnt > 0) {
        e_n = elist[e0]; sn_n = srcArr[e_n]; tn_n = ntype[sn_n];
        pnx = pos[3*sn_n]; pny = pos[3*sn_n+1]; pnz = pos[3*sn_n+2];
        snx = shifts[3*e_n]; sny = shifts[3*e_n+1]; snz = shifts[3*e_n+2];
    }
    for (int t = 0; t < cnt; t++) {
        const int tn = tn_n;
        const float vx = px - pnx + snx;
        const float vy = py - pny + sny;
        const float vz = pz - pnz + snz;
        if (t + 1 < cnt) {
            e_n = elist[e0 + t + 1]; sn_n = srcArr[e_n]; tn_n = ntype[sn_n];
            pnx = pos[3*sn_n]; pny = pos[3*sn_n+1]; pnz = pos[3*sn_n+2];
            snx = shifts[3*e_n]; sny = shifts[3*e_n+1]; snz = shifts[3*e_n+2];
        }
        const float r = sqrtf(vx*vx + vy*vy + vz*vz) + 1e-9f;
        const float u = r * (1.0f / 5.5f);
        const float u2 = u*u, u3 = u2*u, u6 = u3*u3;
        const float fcv = 1.0f - 28.0f*u6 + 48.0f*u6*u - 21.0f*u6*u2;
        const float inv = 1.0f / r;
        float rb[6];
        #pragma unroll
        for (int q = 0; q < 6; q++)
            rb[q] = RBF_NORM * __sinf(r * fr[q]) * inv * fcv;
        if (lane < 20) {
            const float ux = vx*inv, uy = vy*inv, uz = vz*inv;
            const int lx = c_mx[lane], ly = c_my[lane], lz = c_mz[lane];
            float v = 1.f;
            for (int i = 0; i < lx; i++) v *= ux;
            for (int i = 0; i < ly; i++) v *= uy;
            for (int i = 0; i < lz; i++) v *= uz;
            eS[lane] = v;
        } else if (lane < 29) {
            const int c = lane - 20, m = c % 3;
            const float ed = (m == 0) ? ed0 : ((m == 1) ? ed1 : ed2);
            eS[lane] = Wemb[3*tn + c/3] * ed;
        } else if (lane >= 32 && lane < 56) {
            float s = 0.f;
            #pragma unroll
            for (int q = 0; q < 6; q++) s += rb[q] * wrt[q];
            eS[lane - 3] = s;
        }
        __syncthreads();
        #pragma unroll
        for (int k = 0; k < 17; k++)
            acc[k] += eS[ridx[k]] * eS[aidx[k]] * eS[cidx[k]];
        __syncthreads();
    }
    #pragma unroll
    for (int k = 0; k < 17; k++) {
        const int i = lane + 64 * k;
        if (i < 1080) { A[(long)n*1080 + i] = acc[k]; Als[i] = acc[k]; }
    }
    __syncthreads();
    symm_from_lds(Als, Bls, lane);
    __syncthreads();
    // Bls -> global Bf (for k_chi)
    for (int i = lane; i < 324; i += 64) Bf[(long)n*324 + i] = Bls[i];
    // fused GEMV vs even W1 rows
    float p0 = 0.f, p1 = 0.f, p2 = 0.f, p3 = 0.f;
    for (int q = 0; q < 324; q += 4) {
        const float w0 = W1[(size_t)(2*q    )*64 + lane];
        const float w1 = W1[(size_t)(2*q + 2)*64 + lane];
        const float w2 = W1[(size_t)(2*q + 4)*64 + lane];
        const float w3 = W1[(size_t)(2*q + 6)*64 + lane];
        p0 = fmaf(Bls[q    ], w0, p0);
        p1 = fmaf(Bls[q + 1], w1, p1);
        p2 = fmaf(Bls[q + 2], w2, p2);
        p3 = fmaf(Bls[q + 3], w3, p3);
    }
    P1[(size_t)n*64 + lane] = (p0 + p1) + (p2 + p3);
}

// chi[n,c'] = B[n,:] . W_chi[:,c']
__global__ __launch_bounds__(256) void k_chi(const float* __restrict__ Bf,
                                             const float* __restrict__ W_chi,
                                             float* __restrict__ chi)
{
    const int t = blockIdx.x * 256 + threadIdx.x;
    if (t >= NN * 9) return;
    const int cp = t % 9, n = t / 9;
    const float* b = Bf + (long)n * 324;
    float s = 0.f;
    #pragma unroll 4
    for (int j = 0; j < 324; j += 4) {
        const float4 bv = *(const float4*)(b + j);
        s += bv.x * W_chi[(j+0)*9 + cp] + bv.y * W_chi[(j+1)*9 + cp]
           + bv.z * W_chi[(j+2)*9 + cp] + bv.w * W_chi[(j+3)*9 + cp];
    }
    chi[t] = s;
}

// ---------------------------------------------------------------------------
// Pass 2, gather form. Message accumulation + memory term + symmetrize ->
// B2ls (LDS only, no global B2), then fused GEMV vs odd W1 rows -> P2.
// ---------------------------------------------------------------------------
__global__ __launch_bounds__(64) void k_node2(
    const float* __restrict__ pos, const int* __restrict__ ntype,
    const int* __restrict__ srcArr, const float* __restrict__ shifts,
    const float* __restrict__ Wemb, const float* __restrict__ freqs,
    const float* __restrict__ W_rt, const float* __restrict__ W_Ar,
    const float* __restrict__ W_mem, const int* __restrict__ offs,
    const int* __restrict__ indeg, const int* __restrict__ elist,
    const float* __restrict__ chi, const float* __restrict__ A,
    const float* __restrict__ W1, float* __restrict__ P2)
{
    __shared__ float eS[80];     // ang, codechi[20..28], radtB[29..52], radtA[53..76]
    __shared__ float Als[1080];
    __shared__ float Qls[1080];
    __shared__ float Wm[144];
    __shared__ float B2ls[324];
    const int n = blockIdx.x, lane = threadIdx.x;
    #pragma unroll
    for (int k = 0; k < 17; k++) {
        const int i = lane + 64 * k;
        if (i < 1080) Als[i] = A[(long)n*1080 + i];
    }
    Wm[lane] = W_mem[lane];
    Wm[lane + 64] = W_mem[lane + 64];
    if (lane < 16) Wm[lane + 128] = W_mem[lane + 128];
    int ridx[17], aidx[17], cidx[17];
    float acc[17];
    #pragma unroll
    for (int k = 0; k < 17; k++) {
        acc[k] = 0.f;
        const int i = lane + 64 * k;
        const int ii = (i < 1080) ? i : 0;
        const int s2 = ii / 180, rem = ii - s2 * 180;
        const int a = rem / 9, c = rem - a * 9;
        ridx[k] = 29 + l_of_a(a) * 6 + s2; aidx[k] = a; cidx[k] = 20 + c;
    }
    const float px = pos[3*n], py = pos[3*n+1], pz = pos[3*n+2];
    const float ed0 = Wemb[3*ntype[n]], ed1 = Wemb[3*ntype[n]+1],
                ed2 = Wemb[3*ntype[n]+2];
    float fr[6];
    #pragma unroll
    for (int q = 0; q < 6; q++) fr[q] = freqs[q];
    float wrtB[6], wrtA[6];
    if (lane >= 32 && lane < 56) {
        const int j = lane - 32, l = j / 6, s2 = j % 6;
        #pragma unroll
        for (int q = 0; q < 6; q++) {
            wrtB[q] = W_rt[(l*6 + q)*6 + s2];
            wrtA[q] = W_Ar[(l*6 + q)*6 + s2];
        }
    }
    __syncthreads();
    const int e0 = offs[n], cnt = indeg[n];
    int e_n = 0, sn_n = 0, tn_n = 0;
    float pnx = 0, pny = 0, pnz = 0, snx = 0, sny = 0, snz = 0, chin = 0.f;
    float an[17];
    #pragma unroll
    for (int k = 0; k < 17; k++) an[k] = 0.f;
    if (cnt > 0) {
        e_n = elist[e0]; sn_n = srcArr[e_n]; tn_n = ntype[sn_n];
        pnx = pos[3*sn_n]; pny = pos[3*sn_n+1]; pnz = pos[3*sn_n+2];
        snx = shifts[3*e_n]; sny = shifts[3*e_n+1]; snz = shifts[3*e_n+2];
        if (lane >= 20 && lane < 29) chin = chi[sn_n*9 + (lane - 20)];
        const float* ar = A + (long)sn_n * 1080;
        #pragma unroll
        for (int k = 0; k < 17; k++) {
            const int i = lane + 64 * k;
            if (i < 1080) an[k] = ar[i];
        }
    }
    for (int t = 0; t < cnt; t++) {
        const int tn = tn_n;
        const float chiv = chin;
        const float vx = px - pnx + snx;
        const float vy = py - pny + sny;
        const float vz = pz - pnz + snz;
        float av[17];
        #pragma unroll
        for (int k = 0; k < 17; k++) av[k] = an[k];
        if (t + 1 < cnt) {
            e_n = elist[e0 + t + 1]; sn_n = srcArr[e_n]; tn_n = ntype[sn_n];
            pnx = pos[3*sn_n]; pny = pos[3*sn_n+1]; pnz = pos[3*sn_n+2];
            snx = shifts[3*e_n]; sny = shifts[3*e_n+1]; snz = shifts[3*e_n+2];
            if (lane >= 20 && lane < 29) chin = chi[sn_n*9 + (lane - 20)];
            const float* ar = A + (long)sn_n * 1080;
            #pragma unroll
            for (int k = 0; k < 17; k++) {
                const int i = lane + 64 * k;
                if (i < 1080) an[k] = ar[i];
            }
        }
        const float r = sqrtf(vx*vx + vy*vy + vz*vz) + 1e-9f;
        const float u = r * (1.0f / 5.5f);
        const float u2 = u*u, u3 = u2*u, u6 = u3*u3;
        const float fcv = 1.0f - 28.0f*u6 + 48.0f*u6*u - 21.0f*u6*u2;
        const float inv = 1.0f / r;
        float rb[6];
        #pragma unroll
        for (int q = 0; q < 6; q++)
            rb[q] = RBF_NORM * __sinf(r * fr[q]) * inv * fcv;
        if (lane < 20) {
            const float ux = vx*inv, uy = vy*inv, uz = vz*inv;
            const int lx = c_mx[lane], ly = c_my[lane], lz = c_mz[lane];
            float v = 1.f;
            for (int i = 0; i < lx; i++) v *= ux;
            for (int i = 0; i < ly; i++) v *= uy;
            for (int i = 0; i < lz; i++) v *= uz;
            eS[lane] = v;
        } else if (lane < 29) {
            const int c = lane - 20, m = c % 3;
            const float ed = (m == 0) ? ed0 : ((m == 1) ? ed1 : ed2);
            eS[lane] = Wemb[3*tn + c/3] * ed * chiv;
        } else if (lane >= 32 && lane < 56) {
            float sB = 0.f, sA = 0.f;
            #pragma unroll
            for (int q = 0; q < 6; q++) { sB += rb[q]*wrtB[q]; sA += rb[q]*wrtA[q]; }
            eS[lane - 3]  = sB;
            eS[lane + 21] = sA;
        }
        __syncthreads();
        #pragma unroll
        for (int k = 0; k < 17; k++) {
            const int i = lane + 64 * k;
            if (i < 1080)
                acc[k] += eS[ridx[k]] * eS[aidx[k]] * eS[cidx[k]]
                        + av[k] * eS[ridx[k] + 24];
        }
        __syncthreads();
    }
    // memory term + MP_NORM -> Qls
    #pragma unroll
    for (int k = 0; k < 17; k++) {
        const int i = lane + 64 * k;
        if (i < 1080) {
            const int l6 = ridx[k] - 29;
            const int l = l6 / 6, s2v = l6 - 6 * l;
            const int rem = aidx[k] * 9 + (cidx[k] - 20);
            float m = 0.f;
            #pragma unroll
            for (int sp = 0; sp < 6; sp++)
                m += Als[sp*180 + rem] * Wm[l*36 + sp*6 + s2v];
            Qls[i] = acc[k] * MP_NORM + m;
        }
    }
    __syncthreads();
    symm_from_lds(Qls, B2ls, lane);
    __syncthreads();
    // fused GEMV vs odd W1 rows
    float p0 = 0.f, p1 = 0.f, p2 = 0.f, p3 = 0.f;
    for (int q = 0; q < 324; q += 4) {
        const float w0 = W1[(size_t)(2*q + 1)*64 + lane];
        const float w1 = W1[(size_t)(2*q + 3)*64 + lane];
        const float w2 = W1[(size_t)(2*q + 5)*64 + lane];
        const float w3 = W1[(size_t)(2*q + 7)*64 + lane];
        p0 = fmaf(B2ls[q    ], w0, p0);
        p1 = fmaf(B2ls[q + 1], w1, p1);
        p2 = fmaf(B2ls[q + 2], w2, p2);
        p3 = fmaf(B2ls[q + 3], w3, p3);
    }
    P2[(size_t)n*64 + lane] = (p0 + p1) + (p2 + p3);
}

// ---------------------------------------------------------------------------
// Tail: h1 = silu(P1 + P2 + b1); layers 2/3 + per-graph segment sum.
// 1-wave blocks, 4 nodes each, grid 2500 (high TLP).
// ---------------------------------------------------------------------------
__global__ __launch_bounds__(64) void k_tail(
    const float* __restrict__ P1, const float* __restrict__ P2,
    const float* __restrict__ b1, const float* __restrict__ W2,
    const float* __restrict__ b2, const float* __restrict__ W3,
    const float* __restrict__ b3, const int* __restrict__ batch,
    float* __restrict__ out)
{
    __shared__ float h1L[4][64];
    const int lane = threadIdx.x;
    const int nb = blockIdx.x * 4;
    const float bb1 = b1[lane];
    #pragma unroll
    for (int nd = 0; nd < 4; nd++) {
        const float h = P1[(size_t)(nb + nd)*64 + lane]
                      + P2[(size_t)(nb + nd)*64 + lane] + bb1;
        h1L[nd][lane] = h / (1.f + __expf(-h));
    }
    __syncthreads();
    const int oo = lane & 31;
    const float w3v = W3[oo];
    const float b2v = b2[oo];
    #pragma unroll
    for (int pass = 0; pass < 2; pass++) {
        const int nd = 2*pass + (lane >> 5);
        float g = b2v;
        #pragma unroll 8
        for (int k = 0; k < 64; k++)
            g = fmaf(h1L[nd][k], W2[k*32 + oo], g);
        g = g / (1.f + __expf(-g));
        float s = g * w3v;
        s += __shfl_xor(s, 16);
        s += __shfl_xor(s, 8);
        s += __shfl_xor(s, 4);
        s += __shfl_xor(s, 2);
        s += __shfl_xor(s, 1);
        if (oo == 0)
            atomicAdd(out + batch[nb + nd], s + b3[0]);
    }
}

extern "C" void kernel_launch(void* const* d_in, const int* in_sizes, int n_in,
                              void* d_out, int out_size, void* d_ws, size_t ws_size,
                              hipStream_t stream)
{
    const float* pos    = (const float*)d_in[0];
    const int*   ntype  = (const int*)  d_in[1];
    const int*   src    = (const int*)  d_in[2];
    const int*   dst    = (const int*)  d_in[3];
    const float* shifts = (const float*)d_in[4];
    const int*   batch  = (const int*)  d_in[5];
    const float* Wemb   = (const float*)d_in[6];
    const float* freqs  = (const float*)d_in[7];
    const float* W_rt   = (const float*)d_in[8];
    const float* W_mem  = (const float*)d_in[9];
    const float* W_Ar   = (const float*)d_in[10];
    const float* W_chi  = (const float*)d_in[11];
    const float* W1     = (const float*)d_in[12];
    const float* b1     = (const float*)d_in[13];
    const float* W2     = (const float*)d_in[14];
    const float* b2     = (const float*)d_in[15];
    const float* W3     = (const float*)d_in[16];
    const float* b3     = (const float*)d_in[17];

    float* ws   = (float*)d_ws;
    float* A    = ws;                        // [NN,1080]
    float* Bf   = A   + (size_t)NN * 1080;   // [NN,324]
    float* P1   = Bf  + (size_t)NN * 324;    // [NN,64]
    float* P2   = P1  + (size_t)NN * 64;     // [NN,64]
    float* chi  = P2  + (size_t)NN * 64;     // [NN,9]
    int*   indeg  = (int*)(chi + (size_t)NN * 9);
    int*   offs   = indeg  + 10240;
    int*   cursor = offs   + 10240;
    int*   elist  = cursor + 10240;          // [NE]

    hipMemsetAsync(indeg,  0, 10240 * sizeof(int), stream);
    hipMemsetAsync(cursor, 0, 10240 * sizeof(int), stream);
    hipMemsetAsync(d_out,  0, (size_t)out_size * sizeof(float), stream);

    k_hist<<<(NE + 255)/256, 256, 0, stream>>>(pos, src, dst, shifts, indeg);
    k_scan<<<1, 256, 0, stream>>>(indeg, offs);
    k_fill<<<(NE + 255)/256, 256, 0, stream>>>(pos, src, dst, shifts, offs,
                                               cursor, elist);
    k_node1<<<NN, 64, 0, stream>>>(pos, ntype, src, shifts, Wemb, freqs, W_rt,
                                   offs, indeg, elist, W1, A, Bf, P1);
    k_chi<<<(NN*9 + 255)/256, 256, 0, stream>>>(Bf, W_chi, chi);
    k_node2<<<NN, 64, 0, stream>>>(pos, ntype, src, shifts, Wemb, freqs, W_rt,
                                   W_Ar, W_mem, offs, indeg, elist, chi, A,
                                   W1, P2);
    k_tail<<<NN/4, 64, 0, stream>>>(P1, P2, b1, W2, b2, W3, b3, batch,
                                    (float*)d_out);
}

// Round 10
// 363.397 us; speedup vs baseline: 1.0768x; 1.0768x over previous
//
#include <hip/hip_runtime.h>
#include <hip/hip_bf16.h>
#include <math.h>

#define NE 80000
#define NN 10000
#define NG 16
#define MP_NORM 0.31622776601683794f   // 1/sqrt(10)
#define RBF_NORM 0.60302268915552724f  // sqrt(2/5.5)

// monomial tables: index -> (lx,ly,lz), l
__constant__ int c_mx[20] = {0, 1,0,0, 2,1,1,0,0,0, 3,2,2,1,1,1,0,0,0,0};
__constant__ int c_my[20] = {0, 0,1,0, 0,1,0,2,1,0, 0,1,0,2,1,0,3,2,1,0};
__constant__ int c_mz[20] = {0, 0,0,1, 0,0,1,0,1,2, 0,0,1,0,1,2,0,1,2,3};

__device__ __forceinline__ int l_of_a(int a) {
    return (a >= 10) ? 3 : ((a >= 4) ? 2 : ((a >= 1) ? 1 : 0));
}

// symmetrize one node's 1080-vector (in LDS) -> 324 outputs
__device__ __forceinline__ void symm_from_lds(const float* Als, float* brow,
                                              int lane) {
    if (lane >= 54) return;
    const int s2 = lane / 9, c = lane - s2 * 9;
    const float* a = Als + s2 * 180 + c;
    float v[20];
    #pragma unroll
    for (int i = 0; i < 20; i++) v[i] = a[i * 9];
    const float o0 = v[0];
    const float o1 = v[1]*v[1] + v[2]*v[2] + v[3]*v[3];
    const float o2 = v[4]*v[4] + 2.f*v[5]*v[5] + 2.f*v[6]*v[6]
                   + v[7]*v[7] + 2.f*v[8]*v[8] + v[9]*v[9];
    const float o3 = v[10]*v[10] + 3.f*v[11]*v[11] + 3.f*v[12]*v[12]
                   + 3.f*v[13]*v[13] + 6.f*v[14]*v[14] + 3.f*v[15]*v[15]
                   + v[16]*v[16] + 3.f*v[17]*v[17] + 3.f*v[18]*v[18] + v[19]*v[19];
    const float o4 = v[1]*v[1]*v[4] + 2.f*v[1]*v[2]*v[5] + 2.f*v[1]*v[3]*v[6]
                   + 2.f*v[2]*v[1]*v[5] + v[2]*v[2]*v[7] + 2.f*v[2]*v[3]*v[8]
                   + 2.f*v[3]*v[1]*v[6] + 2.f*v[3]*v[2]*v[8] + v[3]*v[3]*v[9];
    const float o5 =
        v[1]*(v[4]*v[10] + 3.f*v[5]*v[11] + 3.f*v[6]*v[12] + 3.f*v[7]*v[13]
              + 6.f*v[8]*v[14] + 3.f*v[9]*v[15])
      + v[2]*(3.f*v[4]*v[11] + 3.f*v[5]*v[13] + 6.f*v[6]*v[14] + v[7]*v[16]
              + 3.f*v[8]*v[17] + 3.f*v[9]*v[18])
      + v[3]*(3.f*v[4]*v[12] + 6.f*v[5]*v[14] + 3.f*v[6]*v[15] + 3.f*v[7]*v[17]
              + 3.f*v[8]*v[18] + v[9]*v[19]);
    float* b = brow + s2 * 54 + c;
    b[0]  = o0;
    b[9]  = o1;
    b[18] = o2;
    b[27] = o3;
    b[36] = o4;
    b[45] = o5;
}

// ---------------------------------------------------------------------------
// CSR build: histogram, scan, fill (fill also precomputes per-active-edge
// geometry (ux,uy,uz,r), source node, and the 9-element edge code).
// ---------------------------------------------------------------------------
__global__ __launch_bounds__(256) void k_hist(
    const float* __restrict__ pos, const int* __restrict__ src,
    const int* __restrict__ dst, const float* __restrict__ shifts,
    int* __restrict__ indeg)
{
    const int e = blockIdx.x * 256 + threadIdx.x;
    if (e >= NE) return;
    const int sn = src[e], dn = dst[e];
    const float vx = pos[3*dn+0] - pos[3*sn+0] + shifts[3*e+0];
    const float vy = pos[3*dn+1] - pos[3*sn+1] + shifts[3*e+1];
    const float vz = pos[3*dn+2] - pos[3*sn+2] + shifts[3*e+2];
    const float r = sqrtf(vx*vx + vy*vy + vz*vz) + 1e-9f;
    if (r * (1.0f / 5.5f) < 1.0f) atomicAdd(&indeg[dn], 1);
}

__global__ __launch_bounds__(256) void k_scan(const int* __restrict__ indeg,
                                              int* __restrict__ offs)
{
    __shared__ int part[256];
    const int t = threadIdx.x;
    int s = 0;
    for (int i = t * 40; i < t * 40 + 40; i++)
        if (i < NN) s += indeg[i];
    part[t] = s;
    __syncthreads();
    if (t == 0) {
        int run = 0;
        for (int i = 0; i < 256; i++) { int v = part[i]; part[i] = run; run += v; }
    }
    __syncthreads();
    int run = part[t];
    for (int i = t * 40; i < t * 40 + 40; i++) {
        if (i < NN) { offs[i] = run; run += indeg[i]; }
    }
}

__global__ __launch_bounds__(256) void k_fill(
    const float* __restrict__ pos, const int* __restrict__ src,
    const int* __restrict__ dst, const float* __restrict__ shifts,
    const int* __restrict__ ntype, const float* __restrict__ Wemb,
    const int* __restrict__ offs, int* __restrict__ cursor,
    int* __restrict__ esrc, float4* __restrict__ egeo,
    float* __restrict__ ecode)
{
    const int e = blockIdx.x * 256 + threadIdx.x;
    if (e >= NE) return;
    const int sn = src[e], dn = dst[e];
    const float vx = pos[3*dn+0] - pos[3*sn+0] + shifts[3*e+0];
    const float vy = pos[3*dn+1] - pos[3*sn+1] + shifts[3*e+1];
    const float vz = pos[3*dn+2] - pos[3*sn+2] + shifts[3*e+2];
    const float r = sqrtf(vx*vx + vy*vy + vz*vz) + 1e-9f;
    if (r * (1.0f / 5.5f) < 1.0f) {
        const int p = offs[dn] + atomicAdd(&cursor[dn], 1);
        esrc[p] = sn;
        const float inv = 1.0f / r;
        egeo[p] = make_float4(vx*inv, vy*inv, vz*inv, r);
        const int ts = ntype[sn], td = ntype[dn];
        const float es0 = Wemb[3*ts], es1 = Wemb[3*ts+1], es2 = Wemb[3*ts+2];
        const float ed0 = Wemb[3*td], ed1 = Wemb[3*td+1], ed2 = Wemb[3*td+2];
        float* cp = ecode + (size_t)p * 9;
        cp[0] = es0*ed0; cp[1] = es0*ed1; cp[2] = es0*ed2;
        cp[3] = es1*ed0; cp[4] = es1*ed1; cp[5] = es1*ed2;
        cp[6] = es2*ed0; cp[7] = es2*ed1; cp[8] = es2*ed2;
    }
}

// ---------------------------------------------------------------------------
// Pass 1: one wave per node, barrier-free edge loop. Per-edge table held in a
// per-lane register (slot = lane): ang 0..19 | code 20..28 | radt 29..52;
// cross-lane reads via __shfl (ds_bpermute, no barrier, no drain).
// Epilogue: A write, symmetrize -> Bls, fused chi, fused GEMV (even W1 rows).
// ---------------------------------------------------------------------------
__global__ __launch_bounds__(64) void k_node1(
    const float* __restrict__ freqs, const float* __restrict__ W_rt,
    const int* __restrict__ offs, const int* __restrict__ indeg,
    const int* __restrict__ esrc, const float4* __restrict__ egeo,
    const float* __restrict__ ecode, const float* __restrict__ W1,
    const float* __restrict__ W_chi,
    float* __restrict__ A, float* __restrict__ chi, float* __restrict__ P1)
{
    __shared__ float Als[1080];
    __shared__ float Bls[324];
    const int n = blockIdx.x, lane = threadIdx.x;
    int pk[17];
    float acc[17];
    #pragma unroll
    for (int k = 0; k < 17; k++) {
        acc[k] = 0.f;
        const int i = lane + 64 * k;
        const int ii = (i < 1080) ? i : 0;
        const int s2 = ii / 180, rem = ii - s2 * 180;
        const int a = rem / 9, c = rem - a * 9;
        pk[k] = (29 + l_of_a(a) * 6 + s2) | (a << 8) | ((20 + c) << 16);
    }
    float fr[6];
    #pragma unroll
    for (int q = 0; q < 6; q++) fr[q] = freqs[q];
    float wrt[6];
    if (lane >= 29 && lane < 53) {
        const int j = lane - 29, l = j / 6, s2 = j % 6;
        #pragma unroll
        for (int q = 0; q < 6; q++) wrt[q] = W_rt[(l*6 + q)*6 + s2];
    }
    int mlx = 0, mly = 0, mlz = 0;
    if (lane < 20) { mlx = c_mx[lane]; mly = c_my[lane]; mlz = c_mz[lane]; }
    const int e0 = offs[n], cnt = indeg[n];
    float4 geo = make_float4(0.f, 0.f, 0.f, 1.f);
    float ecd = 0.f;
    if (cnt > 0) {
        geo = egeo[e0];
        if (lane >= 20 && lane < 29) ecd = ecode[(size_t)e0*9 + lane - 20];
    }
    for (int t = 0; t < cnt; t++) {
        const float4 g = geo;
        const float ec = ecd;
        if (t + 1 < cnt) {
            geo = egeo[e0 + t + 1];
            if (lane >= 20 && lane < 29)
                ecd = ecode[(size_t)(e0 + t + 1)*9 + lane - 20];
        }
        float regX = ec;
        if (lane < 20) {
            float v = 1.f;
            for (int i = 0; i < mlx; i++) v *= g.x;
            for (int i = 0; i < mly; i++) v *= g.y;
            for (int i = 0; i < mlz; i++) v *= g.z;
            regX = v;
        } else if (lane >= 29 && lane < 53) {
            const float r = g.w;
            const float u = r * (1.0f / 5.5f);
            const float u2 = u*u, u3 = u2*u, u6 = u3*u3;
            const float fcv = 1.0f - 28.0f*u6 + 48.0f*u6*u - 21.0f*u6*u2;
            const float inv = fcv / r;
            float s = 0.f;
            #pragma unroll
            for (int q = 0; q < 6; q++)
                s += RBF_NORM * __sinf(r * fr[q]) * inv * wrt[q];
            regX = s;
        }
        #pragma unroll
        for (int k = 0; k < 17; k++) {
            const int p = pk[k];
            acc[k] += __shfl(regX, p & 255) * __shfl(regX, (p >> 8) & 255)
                    * __shfl(regX, p >> 16);
        }
    }
    #pragma unroll
    for (int k = 0; k < 17; k++) {
        const int i = lane + 64 * k;
        if (i < 1080) { A[(size_t)n*1080 + i] = acc[k]; Als[i] = acc[k]; }
    }
    __syncthreads();
    symm_from_lds(Als, Bls, lane);
    __syncthreads();
    // fused chi: lanes 0..35, 4 partial groups of 81, shfl-reduce
    {
        float s = 0.f;
        const int cc = lane % 9;
        if (lane < 36) {
            const int q0 = (lane / 9) * 81;
            #pragma unroll 3
            for (int j = 0; j < 81; j++)
                s = fmaf(Bls[q0 + j], W_chi[(q0 + j) * 9 + cc], s);
        }
        s += __shfl_down(s, 18);
        s += __shfl_down(s, 9);
        if (lane < 9) chi[(size_t)n * 9 + lane] = s;
    }
    // fused GEMV vs even W1 rows
    float p0 = 0.f, p1 = 0.f, p2 = 0.f, p3 = 0.f;
    for (int q = 0; q < 324; q += 4) {
        const float w0 = W1[(size_t)(2*q    )*64 + lane];
        const float w1 = W1[(size_t)(2*q + 2)*64 + lane];
        const float w2 = W1[(size_t)(2*q + 4)*64 + lane];
        const float w3 = W1[(size_t)(2*q + 6)*64 + lane];
        p0 = fmaf(Bls[q    ], w0, p0);
        p1 = fmaf(Bls[q + 1], w1, p1);
        p2 = fmaf(Bls[q + 2], w2, p2);
        p3 = fmaf(Bls[q + 3], w3, p3);
    }
    P1[(size_t)n*64 + lane] = (p0 + p1) + (p2 + p3);
}

// ---------------------------------------------------------------------------
// Pass 2: barrier-free edge loop; regX slots 20..28 hold code*chi(src);
// regY (lanes 29..52) holds radtA. A[src]-row + chi gathers pipelined with
// 2-deep esrc prefetch. Epilogue: memory term, symmetrize, GEMV (odd rows).
// ---------------------------------------------------------------------------
__global__ __launch_bounds__(64) void k_node2(
    const float* __restrict__ freqs, const float* __restrict__ W_rt,
    const float* __restrict__ W_Ar, const float* __restrict__ W_mem,
    const int* __restrict__ offs, const int* __restrict__ indeg,
    const int* __restrict__ esrc, const float4* __restrict__ egeo,
    const float* __restrict__ ecode, const float* __restrict__ chi,
    const float* __restrict__ A, const float* __restrict__ W1,
    float* __restrict__ P2)
{
    __shared__ float Als[1080];
    __shared__ float Qls[1080];
    __shared__ float Wm[144];
    __shared__ float B2ls[324];
    const int n = blockIdx.x, lane = threadIdx.x;
    #pragma unroll
    for (int k = 0; k < 17; k++) {
        const int i = lane + 64 * k;
        if (i < 1080) Als[i] = A[(size_t)n*1080 + i];
    }
    Wm[lane] = W_mem[lane];
    Wm[lane + 64] = W_mem[lane + 64];
    if (lane < 16) Wm[lane + 128] = W_mem[lane + 128];
    int pk[17];
    float acc[17];
    #pragma unroll
    for (int k = 0; k < 17; k++) {
        acc[k] = 0.f;
        const int i = lane + 64 * k;
        const int ii = (i < 1080) ? i : 0;
        const int s2 = ii / 180, rem = ii - s2 * 180;
        const int a = rem / 9, c = rem - a * 9;
        pk[k] = (29 + l_of_a(a) * 6 + s2) | (a << 8) | ((20 + c) << 16);
    }
    float fr[6];
    #pragma unroll
    for (int q = 0; q < 6; q++) fr[q] = freqs[q];
    float wrtB[6], wrtA[6];
    if (lane >= 29 && lane < 53) {
        const int j = lane - 29, l = j / 6, s2 = j % 6;
        #pragma unroll
        for (int q = 0; q < 6; q++) {
            wrtB[q] = W_rt[(l*6 + q)*6 + s2];
            wrtA[q] = W_Ar[(l*6 + q)*6 + s2];
        }
    }
    int mlx = 0, mly = 0, mlz = 0;
    if (lane < 20) { mlx = c_mx[lane]; mly = c_my[lane]; mlz = c_mz[lane]; }
    __syncthreads();   // Als/Wm visible; after this the loop is barrier-free
    const int e0 = offs[n], cnt = indeg[n];
    int sn1 = 0, sn2 = 0;
    float4 geo = make_float4(0.f, 0.f, 0.f, 1.f);
    float ecd = 0.f, chin = 0.f;
    float an[17];
    #pragma unroll
    for (int k = 0; k < 17; k++) an[k] = 0.f;
    if (cnt > 0) {
        sn1 = esrc[e0];
        geo = egeo[e0];
        if (lane >= 20 && lane < 29) {
            ecd  = ecode[(size_t)e0*9 + lane - 20];
            chin = chi[(size_t)sn1*9 + lane - 20];
        }
        const float* ar = A + (size_t)sn1 * 1080;
        #pragma unroll
        for (int k = 0; k < 17; k++) {
            const int i = lane + 64 * k;
            if (i < 1080) an[k] = ar[i];
        }
    }
    if (cnt > 1) sn2 = esrc[e0 + 1];
    for (int t = 0; t < cnt; t++) {
        const float4 g = geo;
        const float ec = ecd, ch = chin;
        float av[17];
        #pragma unroll
        for (int k = 0; k < 17; k++) av[k] = an[k];
        if (t + 1 < cnt) {
            geo = egeo[e0 + t + 1];
            if (lane >= 20 && lane < 29) {
                ecd  = ecode[(size_t)(e0 + t + 1)*9 + lane - 20];
                chin = chi[(size_t)sn2*9 + lane - 20];
            }
            const float* ar = A + (size_t)sn2 * 1080;
            #pragma unroll
            for (int k = 0; k < 17; k++) {
                const int i = lane + 64 * k;
                if (i < 1080) an[k] = ar[i];
            }
            sn1 = sn2;
            if (t + 2 < cnt) sn2 = esrc[e0 + t + 2];
        }
        float regX = ec * ch;
        float regY = 0.f;
        if (lane < 20) {
            float v = 1.f;
            for (int i = 0; i < mlx; i++) v *= g.x;
            for (int i = 0; i < mly; i++) v *= g.y;
            for (int i = 0; i < mlz; i++) v *= g.z;
            regX = v;
        } else if (lane >= 29 && lane < 53) {
            const float r = g.w;
            const float u = r * (1.0f / 5.5f);
            const float u2 = u*u, u3 = u2*u, u6 = u3*u3;
            const float fcv = 1.0f - 28.0f*u6 + 48.0f*u6*u - 21.0f*u6*u2;
            const float inv = fcv / r;
            float sB = 0.f, sA = 0.f;
            #pragma unroll
            for (int q = 0; q < 6; q++) {
                const float rb = RBF_NORM * __sinf(r * fr[q]) * inv;
                sB = fmaf(rb, wrtB[q], sB);
                sA = fmaf(rb, wrtA[q], sA);
            }
            regX = sB;
            regY = sA;
        }
        #pragma unroll
        for (int k = 0; k < 17; k++) {
            const int p = pk[k];
            const float rB = __shfl(regX, p & 255);
            const float rA = __shfl(regY, p & 255);
            acc[k] += rB * __shfl(regX, (p >> 8) & 255)
                         * __shfl(regX, p >> 16)
                    + av[k] * rA;
        }
    }
    // memory term + MP_NORM -> Qls
    #pragma unroll
    for (int k = 0; k < 17; k++) {
        const int i = lane + 64 * k;
        if (i < 1080) {
            const int p = pk[k];
            const int l6 = (p & 255) - 29;
            const int l = l6 / 6, s2v = l6 - 6 * l;
            const int rem = ((p >> 8) & 255) * 9 + ((p >> 16) - 20);
            float m = 0.f;
            #pragma unroll
            for (int sp = 0; sp < 6; sp++)
                m += Als[sp*180 + rem] * Wm[l*36 + sp*6 + s2v];
            Qls[i] = acc[k] * MP_NORM + m;
        }
    }
    __syncthreads();
    symm_from_lds(Qls, B2ls, lane);
    __syncthreads();
    // fused GEMV vs odd W1 rows
    float p0 = 0.f, p1 = 0.f, p2 = 0.f, p3 = 0.f;
    for (int q = 0; q < 324; q += 4) {
        const float w0 = W1[(size_t)(2*q + 1)*64 + lane];
        const float w1 = W1[(size_t)(2*q + 3)*64 + lane];
        const float w2 = W1[(size_t)(2*q + 5)*64 + lane];
        const float w3 = W1[(size_t)(2*q + 7)*64 + lane];
        p0 = fmaf(B2ls[q    ], w0, p0);
        p1 = fmaf(B2ls[q + 1], w1, p1);
        p2 = fmaf(B2ls[q + 2], w2, p2);
        p3 = fmaf(B2ls[q + 3], w3, p3);
    }
    P2[(size_t)n*64 + lane] = (p0 + p1) + (p2 + p3);
}

// ---------------------------------------------------------------------------
// Tail: h1 = silu(P1 + P2 + b1); layers 2/3 + per-graph segment sum.
// ---------------------------------------------------------------------------
__global__ __launch_bounds__(64) void k_tail(
    const float* __restrict__ P1, const float* __restrict__ P2,
    const float* __restrict__ b1, const float* __restrict__ W2,
    const float* __restrict__ b2, const float* __restrict__ W3,
    const float* __restrict__ b3, const int* __restrict__ batch,
    float* __restrict__ out)
{
    __shared__ float h1L[4][64];
    const int lane = threadIdx.x;
    const int nb = blockIdx.x * 4;
    const float bb1 = b1[lane];
    #pragma unroll
    for (int nd = 0; nd < 4; nd++) {
        const float h = P1[(size_t)(nb + nd)*64 + lane]
                      + P2[(size_t)(nb + nd)*64 + lane] + bb1;
        h1L[nd][lane] = h / (1.f + __expf(-h));
    }
    __syncthreads();
    const int oo = lane & 31;
    const float w3v = W3[oo];
    const float b2v = b2[oo];
    #pragma unroll
    for (int pass = 0; pass < 2; pass++) {
        const int nd = 2*pass + (lane >> 5);
        float g = b2v;
        #pragma unroll 8
        for (int k = 0; k < 64; k++)
            g = fmaf(h1L[nd][k], W2[k*32 + oo], g);
        g = g / (1.f + __expf(-g));
        float s = g * w3v;
        s += __shfl_xor(s, 16);
        s += __shfl_xor(s, 8);
        s += __shfl_xor(s, 4);
        s += __shfl_xor(s, 2);
        s += __shfl_xor(s, 1);
        if (oo == 0)
            atomicAdd(out + batch[nb + nd], s + b3[0]);
    }
}

extern "C" void kernel_launch(void* const* d_in, const int* in_sizes, int n_in,
                              void* d_out, int out_size, void* d_ws, size_t ws_size,
                              hipStream_t stream)
{
    const float* pos    = (const float*)d_in[0];
    const int*   ntype  = (const int*)  d_in[1];
    const int*   src    = (const int*)  d_in[2];
    const int*   dst    = (const int*)  d_in[3];
    const float* shifts = (const float*)d_in[4];
    const int*   batch  = (const int*)  d_in[5];
    const float* Wemb   = (const float*)d_in[6];
    const float* freqs  = (const float*)d_in[7];
    const float* W_rt   = (const float*)d_in[8];
    const float* W_mem  = (const float*)d_in[9];
    const float* W_Ar   = (const float*)d_in[10];
    const float* W_chi  = (const float*)d_in[11];
    const float* W1     = (const float*)d_in[12];
    const float* b1     = (const float*)d_in[13];
    const float* W2     = (const float*)d_in[14];
    const float* b2     = (const float*)d_in[15];
    const float* W3     = (const float*)d_in[16];
    const float* b3     = (const float*)d_in[17];

    float*  ws    = (float*)d_ws;
    float*  A     = ws;                        // [NN,1080]
    float*  P1    = A    + (size_t)NN * 1080;  // [NN,64]
    float*  P2    = P1   + (size_t)NN * 64;    // [NN,64]
    float*  chi   = P2   + (size_t)NN * 64;    // [NN,9]
    float4* egeo  = (float4*)(chi + (size_t)NN * 9);       // [NE]
    int*    esrc  = (int*)(egeo + NE);                     // [NE]
    float*  ecode = (float*)(esrc + NE);                   // [NE,9]
    int*    indeg  = (int*)(ecode + (size_t)NE * 9);
    int*    offs   = indeg  + 10240;
    int*    cursor = offs   + 10240;

    hipMemsetAsync(indeg,  0, 10240 * sizeof(int), stream);
    hipMemsetAsync(cursor, 0, 10240 * sizeof(int), stream);
    hipMemsetAsync(d_out,  0, (size_t)out_size * sizeof(float), stream);

    k_hist<<<(NE + 255)/256, 256, 0, stream>>>(pos, src, dst, shifts, indeg);
    k_scan<<<1, 256, 0, stream>>>(indeg, offs);
    k_fill<<<(NE + 255)/256, 256, 0, stream>>>(pos, src, dst, shifts, ntype,
                                               Wemb, offs, cursor, esrc, egeo,
                                               ecode);
    k_node1<<<NN, 64, 0, stream>>>(freqs, W_rt, offs, indeg, esrc, egeo, ecode,
                                   W1, W_chi, A, chi, P1);
    k_node2<<<NN, 64, 0, stream>>>(freqs, W_rt, W_Ar, W_mem, offs, indeg, esrc,
                                   egeo, ecode, chi, A, W1, P2);
    k_tail<<<NN/4, 64, 0, stream>>>(P1, P2, b1, W2, b2, W3, b3, batch,
                                    (float*)d_out);
}

// Round 11
// 250.858 us; speedup vs baseline: 1.5598x; 1.4486x over previous
//
#include <hip/hip_runtime.h>
#include <hip/hip_bf16.h>
#include <math.h>

#define NE 80000
#define NN 10000
#define NG 16
#define NBLK 157   // ceil(NN/64)
#define MP_NORM 0.31622776601683794f   // 1/sqrt(10)
#define RBF_NORM 0.60302268915552724f  // sqrt(2/5.5)

// monomial tables: index -> (lx,ly,lz), l
__constant__ int c_mx[20] = {0, 1,0,0, 2,1,1,0,0,0, 3,2,2,1,1,1,0,0,0,0};
__constant__ int c_my[20] = {0, 0,1,0, 0,1,0,2,1,0, 0,1,0,2,1,0,3,2,1,0};
__constant__ int c_mz[20] = {0, 0,0,1, 0,0,1,0,1,2, 0,0,1,0,1,2,0,1,2,3};

__device__ __forceinline__ int l_of_a(int a) {
    return (a >= 10) ? 3 : ((a >= 4) ? 2 : ((a >= 1) ? 1 : 0));
}

// symmetrize one node's 1080-vector (in LDS) -> 324 outputs
__device__ __forceinline__ void symm_from_lds(const float* Als, float* brow,
                                              int lane) {
    if (lane >= 54) return;
    const int s2 = lane / 9, c = lane - s2 * 9;
    const float* a = Als + s2 * 180 + c;
    float v[20];
    #pragma unroll
    for (int i = 0; i < 20; i++) v[i] = a[i * 9];
    const float o0 = v[0];
    const float o1 = v[1]*v[1] + v[2]*v[2] + v[3]*v[3];
    const float o2 = v[4]*v[4] + 2.f*v[5]*v[5] + 2.f*v[6]*v[6]
                   + v[7]*v[7] + 2.f*v[8]*v[8] + v[9]*v[9];
    const float o3 = v[10]*v[10] + 3.f*v[11]*v[11] + 3.f*v[12]*v[12]
                   + 3.f*v[13]*v[13] + 6.f*v[14]*v[14] + 3.f*v[15]*v[15]
                   + v[16]*v[16] + 3.f*v[17]*v[17] + 3.f*v[18]*v[18] + v[19]*v[19];
    const float o4 = v[1]*v[1]*v[4] + 2.f*v[1]*v[2]*v[5] + 2.f*v[1]*v[3]*v[6]
                   + 2.f*v[2]*v[1]*v[5] + v[2]*v[2]*v[7] + 2.f*v[2]*v[3]*v[8]
                   + 2.f*v[3]*v[1]*v[6] + 2.f*v[3]*v[2]*v[8] + v[3]*v[3]*v[9];
    const float o5 =
        v[1]*(v[4]*v[10] + 3.f*v[5]*v[11] + 3.f*v[6]*v[12] + 3.f*v[7]*v[13]
              + 6.f*v[8]*v[14] + 3.f*v[9]*v[15])
      + v[2]*(3.f*v[4]*v[11] + 3.f*v[5]*v[13] + 6.f*v[6]*v[14] + v[7]*v[16]
              + 3.f*v[8]*v[17] + 3.f*v[9]*v[18])
      + v[3]*(3.f*v[4]*v[12] + 6.f*v[5]*v[14] + 3.f*v[6]*v[15] + 3.f*v[7]*v[17]
              + 3.f*v[8]*v[18] + v[9]*v[19]);
    float* b = brow + s2 * 54 + c;
    b[0]  = o0;
    b[9]  = o1;
    b[18] = o2;
    b[27] = o3;
    b[36] = o4;
    b[45] = o5;
}

// ---------------------------------------------------------------------------
// CSR build: histogram, scan, fill (fill also precomputes per-active-edge
// geometry (ux,uy,uz,r), source node, and the 9-element edge code).
// ---------------------------------------------------------------------------
__global__ __launch_bounds__(256) void k_hist(
    const float* __restrict__ pos, const int* __restrict__ src,
    const int* __restrict__ dst, const float* __restrict__ shifts,
    int* __restrict__ indeg)
{
    const int e = blockIdx.x * 256 + threadIdx.x;
    if (e >= NE) return;
    const int sn = src[e], dn = dst[e];
    const float vx = pos[3*dn+0] - pos[3*sn+0] + shifts[3*e+0];
    const float vy = pos[3*dn+1] - pos[3*sn+1] + shifts[3*e+1];
    const float vz = pos[3*dn+2] - pos[3*sn+2] + shifts[3*e+2];
    const float r = sqrtf(vx*vx + vy*vy + vz*vz) + 1e-9f;
    if (r * (1.0f / 5.5f) < 1.0f) atomicAdd(&indeg[dn], 1);
}

__global__ __launch_bounds__(256) void k_scan(const int* __restrict__ indeg,
                                              int* __restrict__ offs)
{
    __shared__ int part[256];
    const int t = threadIdx.x;
    int s = 0;
    for (int i = t * 40; i < t * 40 + 40; i++)
        if (i < NN) s += indeg[i];
    part[t] = s;
    __syncthreads();
    if (t == 0) {
        int run = 0;
        for (int i = 0; i < 256; i++) { int v = part[i]; part[i] = run; run += v; }
    }
    __syncthreads();
    int run = part[t];
    for (int i = t * 40; i < t * 40 + 40; i++) {
        if (i < NN) { offs[i] = run; run += indeg[i]; }
    }
}

__global__ __launch_bounds__(256) void k_fill(
    const float* __restrict__ pos, const int* __restrict__ src,
    const int* __restrict__ dst, const float* __restrict__ shifts,
    const int* __restrict__ ntype, const float* __restrict__ Wemb,
    const int* __restrict__ offs, int* __restrict__ cursor,
    int* __restrict__ esrc, float4* __restrict__ egeo,
    float* __restrict__ ecode)
{
    const int e = blockIdx.x * 256 + threadIdx.x;
    if (e >= NE) return;
    const int sn = src[e], dn = dst[e];
    const float vx = pos[3*dn+0] - pos[3*sn+0] + shifts[3*e+0];
    const float vy = pos[3*dn+1] - pos[3*sn+1] + shifts[3*e+1];
    const float vz = pos[3*dn+2] - pos[3*sn+2] + shifts[3*e+2];
    const float r = sqrtf(vx*vx + vy*vy + vz*vz) + 1e-9f;
    if (r * (1.0f / 5.5f) < 1.0f) {
        const int p = offs[dn] + atomicAdd(&cursor[dn], 1);
        esrc[p] = sn;
        const float inv = 1.0f / r;
        egeo[p] = make_float4(vx*inv, vy*inv, vz*inv, r);
        const int ts = ntype[sn], td = ntype[dn];
        const float es0 = Wemb[3*ts], es1 = Wemb[3*ts+1], es2 = Wemb[3*ts+2];
        const float ed0 = Wemb[3*td], ed1 = Wemb[3*td+1], ed2 = Wemb[3*td+2];
        float* cp = ecode + (size_t)p * 9;
        cp[0] = es0*ed0; cp[1] = es0*ed1; cp[2] = es0*ed2;
        cp[3] = es1*ed0; cp[4] = es1*ed1; cp[5] = es1*ed2;
        cp[6] = es2*ed0; cp[7] = es2*ed1; cp[8] = es2*ed2;
    }
}

// ---------------------------------------------------------------------------
// Pass 1: one wave per node, barrier-free edge loop (register table + shfl).
// Epilogue: A write, symmetrize -> Bls, fused chi, fused GEMV (even W1 rows).
// ---------------------------------------------------------------------------
__global__ __launch_bounds__(64) void k_node1(
    const float* __restrict__ freqs, const float* __restrict__ W_rt,
    const int* __restrict__ offs, const int* __restrict__ indeg,
    const int* __restrict__ esrc, const float4* __restrict__ egeo,
    const float* __restrict__ ecode, const float* __restrict__ W1,
    const float* __restrict__ W_chi,
    float* __restrict__ A, float* __restrict__ chi, float* __restrict__ P1)
{
    __shared__ float Als[1080];
    __shared__ float Bls[324];
    const int n = blockIdx.x, lane = threadIdx.x;
    int pk[17];
    float acc[17];
    #pragma unroll
    for (int k = 0; k < 17; k++) {
        acc[k] = 0.f;
        const int i = lane + 64 * k;
        const int ii = (i < 1080) ? i : 0;
        const int s2 = ii / 180, rem = ii - s2 * 180;
        const int a = rem / 9, c = rem - a * 9;
        pk[k] = (29 + l_of_a(a) * 6 + s2) | (a << 8) | ((20 + c) << 16);
    }
    float fr[6];
    #pragma unroll
    for (int q = 0; q < 6; q++) fr[q] = freqs[q];
    float wrt[6];
    if (lane >= 29 && lane < 53) {
        const int j = lane - 29, l = j / 6, s2 = j % 6;
        #pragma unroll
        for (int q = 0; q < 6; q++) wrt[q] = W_rt[(l*6 + q)*6 + s2];
    }
    int mlx = 0, mly = 0, mlz = 0;
    if (lane < 20) { mlx = c_mx[lane]; mly = c_my[lane]; mlz = c_mz[lane]; }
    const int e0 = offs[n], cnt = indeg[n];
    float4 geo = make_float4(0.f, 0.f, 0.f, 1.f);
    float ecd = 0.f;
    if (cnt > 0) {
        geo = egeo[e0];
        if (lane >= 20 && lane < 29) ecd = ecode[(size_t)e0*9 + lane - 20];
    }
    for (int t = 0; t < cnt; t++) {
        const float4 g = geo;
        const float ec = ecd;
        if (t + 1 < cnt) {
            geo = egeo[e0 + t + 1];
            if (lane >= 20 && lane < 29)
                ecd = ecode[(size_t)(e0 + t + 1)*9 + lane - 20];
        }
        float regX = ec;
        if (lane < 20) {
            float v = 1.f;
            for (int i = 0; i < mlx; i++) v *= g.x;
            for (int i = 0; i < mly; i++) v *= g.y;
            for (int i = 0; i < mlz; i++) v *= g.z;
            regX = v;
        } else if (lane >= 29 && lane < 53) {
            const float r = g.w;
            const float u = r * (1.0f / 5.5f);
            const float u2 = u*u, u3 = u2*u, u6 = u3*u3;
            const float fcv = 1.0f - 28.0f*u6 + 48.0f*u6*u - 21.0f*u6*u2;
            const float inv = fcv / r;
            float s = 0.f;
            #pragma unroll
            for (int q = 0; q < 6; q++)
                s += RBF_NORM * __sinf(r * fr[q]) * inv * wrt[q];
            regX = s;
        }
        #pragma unroll
        for (int k = 0; k < 17; k++) {
            const int p = pk[k];
            acc[k] += __shfl(regX, p & 255) * __shfl(regX, (p >> 8) & 255)
                    * __shfl(regX, p >> 16);
        }
    }
    #pragma unroll
    for (int k = 0; k < 17; k++) {
        const int i = lane + 64 * k;
        if (i < 1080) { A[(size_t)n*1080 + i] = acc[k]; Als[i] = acc[k]; }
    }
    __syncthreads();
    symm_from_lds(Als, Bls, lane);
    __syncthreads();
    // fused chi: lanes 0..35, 4 partial groups of 81, shfl-reduce
    {
        float s = 0.f;
        const int cc = lane % 9;
        if (lane < 36) {
            const int q0 = (lane / 9) * 81;
            #pragma unroll 3
            for (int j = 0; j < 81; j++)
                s = fmaf(Bls[q0 + j], W_chi[(q0 + j) * 9 + cc], s);
        }
        s += __shfl_down(s, 18);
        s += __shfl_down(s, 9);
        if (lane < 9) chi[(size_t)n * 9 + lane] = s;
    }
    // fused GEMV vs even W1 rows
    float p0 = 0.f, p1 = 0.f, p2 = 0.f, p3 = 0.f;
    for (int q = 0; q < 324; q += 4) {
        const float w0 = W1[(size_t)(2*q    )*64 + lane];
        const float w1 = W1[(size_t)(2*q + 2)*64 + lane];
        const float w2 = W1[(size_t)(2*q + 4)*64 + lane];
        const float w3 = W1[(size_t)(2*q + 6)*64 + lane];
        p0 = fmaf(Bls[q    ], w0, p0);
        p1 = fmaf(Bls[q + 1], w1, p1);
        p2 = fmaf(Bls[q + 2], w2, p2);
        p3 = fmaf(Bls[q + 3], w3, p3);
    }
    P1[(size_t)n*64 + lane] = (p0 + p1) + (p2 + p3);
}

// ---------------------------------------------------------------------------
// Pass 2: barrier-free edge loop; regX slots 20..28 hold code*chi(src);
// regY (lanes 29..52) holds radtA. A[src]-row + chi gathers pipelined with
// 2-deep esrc prefetch. Epilogue: memory term, symmetrize, GEMV (odd rows).
// ---------------------------------------------------------------------------
__global__ __launch_bounds__(64) void k_node2(
    const float* __restrict__ freqs, const float* __restrict__ W_rt,
    const float* __restrict__ W_Ar, const float* __restrict__ W_mem,
    const int* __restrict__ offs, const int* __restrict__ indeg,
    const int* __restrict__ esrc, const float4* __restrict__ egeo,
    const float* __restrict__ ecode, const float* __restrict__ chi,
    const float* __restrict__ A, const float* __restrict__ W1,
    float* __restrict__ P2)
{
    __shared__ float Als[1080];
    __shared__ float Qls[1080];
    __shared__ float Wm[144];
    __shared__ float B2ls[324];
    const int n = blockIdx.x, lane = threadIdx.x;
    #pragma unroll
    for (int k = 0; k < 17; k++) {
        const int i = lane + 64 * k;
        if (i < 1080) Als[i] = A[(size_t)n*1080 + i];
    }
    Wm[lane] = W_mem[lane];
    Wm[lane + 64] = W_mem[lane + 64];
    if (lane < 16) Wm[lane + 128] = W_mem[lane + 128];
    int pk[17];
    float acc[17];
    #pragma unroll
    for (int k = 0; k < 17; k++) {
        acc[k] = 0.f;
        const int i = lane + 64 * k;
        const int ii = (i < 1080) ? i : 0;
        const int s2 = ii / 180, rem = ii - s2 * 180;
        const int a = rem / 9, c = rem - a * 9;
        pk[k] = (29 + l_of_a(a) * 6 + s2) | (a << 8) | ((20 + c) << 16);
    }
    float fr[6];
    #pragma unroll
    for (int q = 0; q < 6; q++) fr[q] = freqs[q];
    float wrtB[6], wrtA[6];
    if (lane >= 29 && lane < 53) {
        const int j = lane - 29, l = j / 6, s2 = j % 6;
        #pragma unroll
        for (int q = 0; q < 6; q++) {
            wrtB[q] = W_rt[(l*6 + q)*6 + s2];
            wrtA[q] = W_Ar[(l*6 + q)*6 + s2];
        }
    }
    int mlx = 0, mly = 0, mlz = 0;
    if (lane < 20) { mlx = c_mx[lane]; mly = c_my[lane]; mlz = c_mz[lane]; }
    __syncthreads();   // Als/Wm visible; after this the loop is barrier-free
    const int e0 = offs[n], cnt = indeg[n];
    int sn1 = 0, sn2 = 0;
    float4 geo = make_float4(0.f, 0.f, 0.f, 1.f);
    float ecd = 0.f, chin = 0.f;
    float an[17];
    #pragma unroll
    for (int k = 0; k < 17; k++) an[k] = 0.f;
    if (cnt > 0) {
        sn1 = esrc[e0];
        geo = egeo[e0];
        if (lane >= 20 && lane < 29) {
            ecd  = ecode[(size_t)e0*9 + lane - 20];
            chin = chi[(size_t)sn1*9 + lane - 20];
        }
        const float* ar = A + (size_t)sn1 * 1080;
        #pragma unroll
        for (int k = 0; k < 17; k++) {
            const int i = lane + 64 * k;
            if (i < 1080) an[k] = ar[i];
        }
    }
    if (cnt > 1) sn2 = esrc[e0 + 1];
    for (int t = 0; t < cnt; t++) {
        const float4 g = geo;
        const float ec = ecd, ch = chin;
        float av[17];
        #pragma unroll
        for (int k = 0; k < 17; k++) av[k] = an[k];
        if (t + 1 < cnt) {
            geo = egeo[e0 + t + 1];
            if (lane >= 20 && lane < 29) {
                ecd  = ecode[(size_t)(e0 + t + 1)*9 + lane - 20];
                chin = chi[(size_t)sn2*9 + lane - 20];
            }
            const float* ar = A + (size_t)sn2 * 1080;
            #pragma unroll
            for (int k = 0; k < 17; k++) {
                const int i = lane + 64 * k;
                if (i < 1080) an[k] = ar[i];
            }
            sn1 = sn2;
            if (t + 2 < cnt) sn2 = esrc[e0 + t + 2];
        }
        float regX = ec * ch;
        float regY = 0.f;
        if (lane < 20) {
            float v = 1.f;
            for (int i = 0; i < mlx; i++) v *= g.x;
            for (int i = 0; i < mly; i++) v *= g.y;
            for (int i = 0; i < mlz; i++) v *= g.z;
            regX = v;
        } else if (lane >= 29 && lane < 53) {
            const float r = g.w;
            const float u = r * (1.0f / 5.5f);
            const float u2 = u*u, u3 = u2*u, u6 = u3*u3;
            const float fcv = 1.0f - 28.0f*u6 + 48.0f*u6*u - 21.0f*u6*u2;
            const float inv = fcv / r;
            float sB = 0.f, sA = 0.f;
            #pragma unroll
            for (int q = 0; q < 6; q++) {
                const float rb = RBF_NORM * __sinf(r * fr[q]) * inv;
                sB = fmaf(rb, wrtB[q], sB);
                sA = fmaf(rb, wrtA[q], sA);
            }
            regX = sB;
            regY = sA;
        }
        #pragma unroll
        for (int k = 0; k < 17; k++) {
            const int p = pk[k];
            const float rB = __shfl(regX, p & 255);
            const float rA = __shfl(regY, p & 255);
            acc[k] += rB * __shfl(regX, (p >> 8) & 255)
                         * __shfl(regX, p >> 16)
                    + av[k] * rA;
        }
    }
    // memory term + MP_NORM -> Qls
    #pragma unroll
    for (int k = 0; k < 17; k++) {
        const int i = lane + 64 * k;
        if (i < 1080) {
            const int p = pk[k];
            const int l6 = (p & 255) - 29;
            const int l = l6 / 6, s2v = l6 - 6 * l;
            const int rem = ((p >> 8) & 255) * 9 + ((p >> 16) - 20);
            float m = 0.f;
            #pragma unroll
            for (int sp = 0; sp < 6; sp++)
                m += Als[sp*180 + rem] * Wm[l*36 + sp*6 + s2v];
            Qls[i] = acc[k] * MP_NORM + m;
        }
    }
    __syncthreads();
    symm_from_lds(Qls, B2ls, lane);
    __syncthreads();
    // fused GEMV vs odd W1 rows
    float p0 = 0.f, p1 = 0.f, p2 = 0.f, p3 = 0.f;
    for (int q = 0; q < 324; q += 4) {
        const float w0 = W1[(size_t)(2*q + 1)*64 + lane];
        const float w1 = W1[(size_t)(2*q + 3)*64 + lane];
        const float w2 = W1[(size_t)(2*q + 5)*64 + lane];
        const float w3 = W1[(size_t)(2*q + 7)*64 + lane];
        p0 = fmaf(B2ls[q    ], w0, p0);
        p1 = fmaf(B2ls[q + 1], w1, p1);
        p2 = fmaf(B2ls[q + 2], w2, p2);
        p3 = fmaf(B2ls[q + 3], w3, p3);
    }
    P2[(size_t)n*64 + lane] = (p0 + p1) + (p2 + p3);
}

// ---------------------------------------------------------------------------
// Tail v2: 64 nodes per 256-thread block. h1 in LDS, W2 in LDS; 4 threads
// per node; per-node scalar via 2-step shfl; LDS atomic into gsum[16];
// block writes 16 partials (NO global atomics). k_final reduces partials.
// ---------------------------------------------------------------------------
__global__ __launch_bounds__(256) void k_tail(
    const float* __restrict__ P1, const float* __restrict__ P2,
    const float* __restrict__ b1, const float* __restrict__ W2,
    const float* __restrict__ b2, const float* __restrict__ W3,
    const float* __restrict__ b3, const int* __restrict__ batch,
    float* __restrict__ part)
{
    __shared__ float h1s[64][66];
    __shared__ float W2L[2048];
    __shared__ float gsum[16];
    const int tid = threadIdx.x;
    const int nb = blockIdx.x * 64;
    if (tid < 16) gsum[tid] = 0.f;
    for (int idx = tid; idx < 2048; idx += 256) W2L[idx] = W2[idx];
    for (int idx = tid; idx < 4096; idx += 256) {
        const int nl = idx >> 6, o = idx & 63;
        float h = 0.f;
        if (nb + nl < NN)
            h = P1[(size_t)(nb + nl)*64 + o] + P2[(size_t)(nb + nl)*64 + o]
              + b1[o];
        h1s[nl][o] = h / (1.f + __expf(-h));
    }
    __syncthreads();
    const int nl = tid >> 2, og = (tid & 3) * 8;
    float acc2[8];
    #pragma unroll
    for (int j = 0; j < 8; j++) acc2[j] = b2[og + j];
    #pragma unroll 8
    for (int k = 0; k < 64; k++) {
        const float hv = h1s[nl][k];
        const float4 wA = *(const float4*)&W2L[k*32 + og];
        const float4 wB = *(const float4*)&W2L[k*32 + og + 4];
        acc2[0] = fmaf(hv, wA.x, acc2[0]); acc2[1] = fmaf(hv, wA.y, acc2[1]);
        acc2[2] = fmaf(hv, wA.z, acc2[2]); acc2[3] = fmaf(hv, wA.w, acc2[3]);
        acc2[4] = fmaf(hv, wB.x, acc2[4]); acc2[5] = fmaf(hv, wB.y, acc2[5]);
        acc2[6] = fmaf(hv, wB.z, acc2[6]); acc2[7] = fmaf(hv, wB.w, acc2[7]);
    }
    float s = 0.f;
    #pragma unroll
    for (int j = 0; j < 8; j++) {
        const float g = acc2[j] / (1.f + __expf(-acc2[j]));
        s = fmaf(g, W3[og + j], s);
    }
    s += __shfl_xor(s, 1);
    s += __shfl_xor(s, 2);
    if ((tid & 3) == 0 && nb + nl < NN)
        atomicAdd(&gsum[batch[nb + nl]], s + b3[0]);
    __syncthreads();
    if (tid < 16) part[blockIdx.x * 16 + tid] = gsum[tid];
}

__global__ __launch_bounds__(64) void k_final(const float* __restrict__ part,
                                              float* __restrict__ out)
{
    const int t = threadIdx.x;
    if (t >= 16) return;
    float acc = 0.f;
    for (int b = 0; b < NBLK; b++) acc += part[b * 16 + t];
    out[t] = acc;
}

extern "C" void kernel_launch(void* const* d_in, const int* in_sizes, int n_in,
                              void* d_out, int out_size, void* d_ws, size_t ws_size,
                              hipStream_t stream)
{
    const float* pos    = (const float*)d_in[0];
    const int*   ntype  = (const int*)  d_in[1];
    const int*   src    = (const int*)  d_in[2];
    const int*   dst    = (const int*)  d_in[3];
    const float* shifts = (const float*)d_in[4];
    const int*   batch  = (const int*)  d_in[5];
    const float* Wemb   = (const float*)d_in[6];
    const float* freqs  = (const float*)d_in[7];
    const float* W_rt   = (const float*)d_in[8];
    const float* W_mem  = (const float*)d_in[9];
    const float* W_Ar   = (const float*)d_in[10];
    const float* W_chi  = (const float*)d_in[11];
    const float* W1     = (const float*)d_in[12];
    const float* b1     = (const float*)d_in[13];
    const float* W2     = (const float*)d_in[14];
    const float* b2     = (const float*)d_in[15];
    const float* W3     = (const float*)d_in[16];
    const float* b3     = (const float*)d_in[17];

    float*  ws    = (float*)d_ws;
    float*  A     = ws;                        // [NN,1080]
    float*  P1    = A    + (size_t)NN * 1080;  // [NN,64]
    float*  P2    = P1   + (size_t)NN * 64;    // [NN,64]
    float*  chi   = P2   + (size_t)NN * 64;    // [NN,9]
    float4* egeo  = (float4*)(chi + (size_t)NN * 9);       // [NE]
    int*    esrc  = (int*)(egeo + NE);                     // [NE]
    float*  ecode = (float*)(esrc + NE);                   // [NE,9]
    float*  part  = ecode + (size_t)NE * 9;                // [NBLK,16]
    int*    indeg  = (int*)(part + NBLK * 16);
    int*    offs   = indeg  + 10240;
    int*    cursor = offs   + 10240;

    hipMemsetAsync(indeg,  0, 10240 * sizeof(int), stream);
    hipMemsetAsync(cursor, 0, 10240 * sizeof(int), stream);

    k_hist<<<(NE + 255)/256, 256, 0, stream>>>(pos, src, dst, shifts, indeg);
    k_scan<<<1, 256, 0, stream>>>(indeg, offs);
    k_fill<<<(NE + 255)/256, 256, 0, stream>>>(pos, src, dst, shifts, ntype,
                                               Wemb, offs, cursor, esrc, egeo,
                                               ecode);
    k_node1<<<NN, 64, 0, stream>>>(freqs, W_rt, offs, indeg, esrc, egeo, ecode,
                                   W1, W_chi, A, chi, P1);
    k_node2<<<NN, 64, 0, stream>>>(freqs, W_rt, W_Ar, W_mem, offs, indeg, esrc,
                                   egeo, ecode, chi, A, W1, P2);
    k_tail<<<NBLK, 256, 0, stream>>>(P1, P2, b1, W2, b2, W3, b3, batch, part);
    k_final<<<1, 64, 0, stream>>>(part, (float*)d_out);
}

// Round 12
// 202.211 us; speedup vs baseline: 1.9351x; 1.2406x over previous
//
#include <hip/hip_runtime.h>
#include <hip/hip_bf16.h>
#include <math.h>

#define NE 80000
#define NN 10000
#define NG 16
#define NBLK 157   // ceil(NN/64)
#define MP_NORM 0.31622776601683794f   // 1/sqrt(10)
#define RBF_NORM 0.60302268915552724f  // sqrt(2/5.5)

// monomial tables: index -> (lx,ly,lz), l
__constant__ int c_mx[20] = {0, 1,0,0, 2,1,1,0,0,0, 3,2,2,1,1,1,0,0,0,0};
__constant__ int c_my[20] = {0, 0,1,0, 0,1,0,2,1,0, 0,1,0,2,1,0,3,2,1,0};
__constant__ int c_mz[20] = {0, 0,0,1, 0,0,1,0,1,2, 0,0,1,0,1,2,0,1,2,3};

__device__ __forceinline__ int l_of_a(int a) {
    return (a >= 10) ? 3 : ((a >= 4) ? 2 : ((a >= 1) ? 1 : 0));
}

// symmetrize one node's 1080-vector (in LDS, layout [s][a*9+c]) -> 324
__device__ __forceinline__ void symm_from_lds(const float* Als, float* brow,
                                              int lane) {
    if (lane >= 54) return;
    const int s2 = lane / 9, c = lane - s2 * 9;
    const float* a = Als + s2 * 180 + c;
    float v[20];
    #pragma unroll
    for (int i = 0; i < 20; i++) v[i] = a[i * 9];
    const float o0 = v[0];
    const float o1 = v[1]*v[1] + v[2]*v[2] + v[3]*v[3];
    const float o2 = v[4]*v[4] + 2.f*v[5]*v[5] + 2.f*v[6]*v[6]
                   + v[7]*v[7] + 2.f*v[8]*v[8] + v[9]*v[9];
    const float o3 = v[10]*v[10] + 3.f*v[11]*v[11] + 3.f*v[12]*v[12]
                   + 3.f*v[13]*v[13] + 6.f*v[14]*v[14] + 3.f*v[15]*v[15]
                   + v[16]*v[16] + 3.f*v[17]*v[17] + 3.f*v[18]*v[18] + v[19]*v[19];
    const float o4 = v[1]*v[1]*v[4] + 2.f*v[1]*v[2]*v[5] + 2.f*v[1]*v[3]*v[6]
                   + 2.f*v[2]*v[1]*v[5] + v[2]*v[2]*v[7] + 2.f*v[2]*v[3]*v[8]
                   + 2.f*v[3]*v[1]*v[6] + 2.f*v[3]*v[2]*v[8] + v[3]*v[3]*v[9];
    const float o5 =
        v[1]*(v[4]*v[10] + 3.f*v[5]*v[11] + 3.f*v[6]*v[12] + 3.f*v[7]*v[13]
              + 6.f*v[8]*v[14] + 3.f*v[9]*v[15])
      + v[2]*(3.f*v[4]*v[11] + 3.f*v[5]*v[13] + 6.f*v[6]*v[14] + v[7]*v[16]
              + 3.f*v[8]*v[17] + 3.f*v[9]*v[18])
      + v[3]*(3.f*v[4]*v[12] + 6.f*v[5]*v[14] + 3.f*v[6]*v[15] + 3.f*v[7]*v[17]
              + 3.f*v[8]*v[18] + v[9]*v[19]);
    float* b = brow + s2 * 54 + c;
    b[0]  = o0;
    b[9]  = o1;
    b[18] = o2;
    b[27] = o3;
    b[36] = o4;
    b[45] = o5;
}

// ---------------------------------------------------------------------------
// CSR build: histogram, scan, fill (fill precomputes per-active-edge
// geometry, source node, and 9-element edge code).
// ---------------------------------------------------------------------------
__global__ __launch_bounds__(256) void k_hist(
    const float* __restrict__ pos, const int* __restrict__ src,
    const int* __restrict__ dst, const float* __restrict__ shifts,
    int* __restrict__ indeg)
{
    const int e = blockIdx.x * 256 + threadIdx.x;
    if (e >= NE) return;
    const int sn = src[e], dn = dst[e];
    const float vx = pos[3*dn+0] - pos[3*sn+0] + shifts[3*e+0];
    const float vy = pos[3*dn+1] - pos[3*sn+1] + shifts[3*e+1];
    const float vz = pos[3*dn+2] - pos[3*sn+2] + shifts[3*e+2];
    const float r = sqrtf(vx*vx + vy*vy + vz*vz) + 1e-9f;
    if (r * (1.0f / 5.5f) < 1.0f) atomicAdd(&indeg[dn], 1);
}

__global__ __launch_bounds__(256) void k_scan(const int* __restrict__ indeg,
                                              int* __restrict__ offs)
{
    __shared__ int part[256];
    const int t = threadIdx.x;
    int s = 0;
    for (int i = t * 40; i < t * 40 + 40; i++)
        if (i < NN) s += indeg[i];
    part[t] = s;
    __syncthreads();
    if (t == 0) {
        int run = 0;
        for (int i = 0; i < 256; i++) { int v = part[i]; part[i] = run; run += v; }
    }
    __syncthreads();
    int run = part[t];
    for (int i = t * 40; i < t * 40 + 40; i++) {
        if (i < NN) { offs[i] = run; run += indeg[i]; }
    }
}

__global__ __launch_bounds__(256) void k_fill(
    const float* __restrict__ pos, const int* __restrict__ src,
    const int* __restrict__ dst, const float* __restrict__ shifts,
    const int* __restrict__ ntype, const float* __restrict__ Wemb,
    const int* __restrict__ offs, int* __restrict__ cursor,
    int* __restrict__ esrc, float4* __restrict__ egeo,
    float* __restrict__ ecode)
{
    const int e = blockIdx.x * 256 + threadIdx.x;
    if (e >= NE) return;
    const int sn = src[e], dn = dst[e];
    const float vx = pos[3*dn+0] - pos[3*sn+0] + shifts[3*e+0];
    const float vy = pos[3*dn+1] - pos[3*sn+1] + shifts[3*e+1];
    const float vz = pos[3*dn+2] - pos[3*sn+2] + shifts[3*e+2];
    const float r = sqrtf(vx*vx + vy*vy + vz*vz) + 1e-9f;
    if (r * (1.0f / 5.5f) < 1.0f) {
        const int p = offs[dn] + atomicAdd(&cursor[dn], 1);
        esrc[p] = sn;
        const float inv = 1.0f / r;
        egeo[p] = make_float4(vx*inv, vy*inv, vz*inv, r);
        const int ts = ntype[sn], td = ntype[dn];
        const float es0 = Wemb[3*ts], es1 = Wemb[3*ts+1], es2 = Wemb[3*ts+2];
        const float ed0 = Wemb[3*td], ed1 = Wemb[3*td+1], ed2 = Wemb[3*td+2];
        float* cp = ecode + (size_t)p * 9;
        cp[0] = es0*ed0; cp[1] = es0*ed1; cp[2] = es0*ed2;
        cp[3] = es1*ed0; cp[4] = es1*ed1; cp[5] = es1*ed2;
        cp[6] = es2*ed0; cp[7] = es2*ed1; cp[8] = es2*ed2;
    }
}

// ---------------------------------------------------------------------------
// Pass 1: one wave/node, barrier-free edge loop, factored triple-product:
// pairs p=lane+64j (j<3, p<180), acc[j][s] += rad[l_p,s]*(ang[a_p]*code[c_p]).
// Epilogue: A write, symmetrize -> Bls, 63-lane pipelined chi, pipelined
// GEMV vs even W1 rows -> P1.
// ---------------------------------------------------------------------------
__global__ __launch_bounds__(64) void k_node1(
    const float* __restrict__ freqs, const float* __restrict__ W_rt,
    const int* __restrict__ offs, const int* __restrict__ indeg,
    const int* __restrict__ esrc, const float4* __restrict__ egeo,
    const float* __restrict__ ecode, const float* __restrict__ W1,
    const float* __restrict__ W_chi,
    float* __restrict__ A, float* __restrict__ chi, float* __restrict__ P1)
{
    __shared__ float Als[1080];
    __shared__ float Bls[324];
    const int n = blockIdx.x, lane = threadIdx.x;
    int aslot[3], cslot[3], rslot[3];
    float acc[3][6];
    #pragma unroll
    for (int j = 0; j < 3; j++) {
        const int p = lane + 64 * j;
        const int pc = (p < 180) ? p : 0;
        aslot[j] = pc / 9;
        cslot[j] = 20 + pc % 9;
        rslot[j] = 29 + 6 * l_of_a(pc / 9);
        #pragma unroll
        for (int s = 0; s < 6; s++) acc[j][s] = 0.f;
    }
    float fr[6];
    #pragma unroll
    for (int q = 0; q < 6; q++) fr[q] = freqs[q];
    float wrt[6];
    if (lane >= 29 && lane < 53) {
        const int j = lane - 29, l = j / 6, s2 = j % 6;
        #pragma unroll
        for (int q = 0; q < 6; q++) wrt[q] = W_rt[(l*6 + q)*6 + s2];
    }
    int mlx = 0, mly = 0, mlz = 0;
    if (lane < 20) { mlx = c_mx[lane]; mly = c_my[lane]; mlz = c_mz[lane]; }
    const int e0 = offs[n], cnt = indeg[n];
    float4 geo = make_float4(0.f, 0.f, 0.f, 1.f);
    float ecd = 0.f;
    if (cnt > 0) {
        geo = egeo[e0];
        if (lane >= 20 && lane < 29) ecd = ecode[(size_t)e0*9 + lane - 20];
    }
    for (int t = 0; t < cnt; t++) {
        const float4 g = geo;
        const float ec = ecd;
        if (t + 1 < cnt) {
            geo = egeo[e0 + t + 1];
            if (lane >= 20 && lane < 29)
                ecd = ecode[(size_t)(e0 + t + 1)*9 + lane - 20];
        }
        float regX = ec;
        if (lane < 20) {
            float v = 1.f;
            for (int i = 0; i < mlx; i++) v *= g.x;
            for (int i = 0; i < mly; i++) v *= g.y;
            for (int i = 0; i < mlz; i++) v *= g.z;
            regX = v;
        } else if (lane >= 29 && lane < 53) {
            const float r = g.w;
            const float u = r * (1.0f / 5.5f);
            const float u2 = u*u, u3 = u2*u, u6 = u3*u3;
            const float fcv = 1.0f - 28.0f*u6 + 48.0f*u6*u - 21.0f*u6*u2;
            const float inv = fcv / r;
            float s = 0.f;
            #pragma unroll
            for (int q = 0; q < 6; q++)
                s += RBF_NORM * __sinf(r * fr[q]) * inv * wrt[q];
            regX = s;
        }
        float pp[3];
        #pragma unroll
        for (int j = 0; j < 3; j++)
            pp[j] = __shfl(regX, aslot[j]) * __shfl(regX, cslot[j]);
        #pragma unroll
        for (int j = 0; j < 3; j++) {
            #pragma unroll
            for (int s = 0; s < 6; s++)
                acc[j][s] = fmaf(__shfl(regX, rslot[j] + s), pp[j], acc[j][s]);
        }
    }
    #pragma unroll
    for (int j = 0; j < 3; j++) {
        const int p = lane + 64 * j;
        if (p < 180) {
            #pragma unroll
            for (int s = 0; s < 6; s++) {
                A[(size_t)n*1080 + s*180 + p] = acc[j][s];
                Als[s*180 + p] = acc[j][s];
            }
        }
    }
    __syncthreads();
    symm_from_lds(Als, Bls, lane);
    __syncthreads();
    // 63-lane pipelined chi: group g=lane/9 covers j in [47g, min(324,47g+47))
    {
        float s = 0.f;
        if (lane < 63) {
            const int cc = lane % 9, gg = lane / 9;
            const int jb = gg * 47;
            const int je = (jb + 47 < 324) ? (jb + 47) : 324;
            float wc = W_chi[jb * 9 + cc];
            for (int j = jb; j < je; j++) {
                const float wn = (j + 1 < je) ? W_chi[(j + 1) * 9 + cc] : 0.f;
                s = fmaf(Bls[j], wc, s);
                wc = wn;
            }
        }
        float tt;
        tt = __shfl(s, lane + 36); if (lane < 27) s += tt;
        tt = __shfl(s, lane + 18); if (lane < 18) s += tt;
        tt = __shfl(s, lane + 9);
        if (lane < 9) chi[(size_t)n * 9 + lane] = s + tt;
    }
    // pipelined GEMV vs even W1 rows (324 = 54 x 6)
    {
        float cur[6], nxt[6];
        #pragma unroll
        for (int u = 0; u < 6; u++) cur[u] = W1[(size_t)(2*u)*64 + lane];
        float s0=0.f, s1=0.f, s2=0.f, s3=0.f, s4=0.f, s5=0.f;
        for (int q = 0; q < 324; q += 6) {
            const int qn = q + 6;
            if (qn < 324) {
                #pragma unroll
                for (int u = 0; u < 6; u++)
                    nxt[u] = W1[(size_t)(2*(qn+u))*64 + lane];
            }
            s0 = fmaf(Bls[q+0], cur[0], s0);
            s1 = fmaf(Bls[q+1], cur[1], s1);
            s2 = fmaf(Bls[q+2], cur[2], s2);
            s3 = fmaf(Bls[q+3], cur[3], s3);
            s4 = fmaf(Bls[q+4], cur[4], s4);
            s5 = fmaf(Bls[q+5], cur[5], s5);
            #pragma unroll
            for (int u = 0; u < 6; u++) cur[u] = nxt[u];
        }
        P1[(size_t)n*64 + lane] = ((s0 + s1) + (s2 + s3)) + (s4 + s5);
    }
}

// ---------------------------------------------------------------------------
// Pass 2: barrier-free edge loop with factored triple-product + A[src]
// gather in [j][s] layout (one-edge-ahead). Epilogue: memory term (hoisted
// Als reads), symmetrize, pipelined GEMV vs odd W1 rows -> P2.
// ---------------------------------------------------------------------------
__global__ __launch_bounds__(64) void k_node2(
    const float* __restrict__ freqs, const float* __restrict__ W_rt,
    const float* __restrict__ W_Ar, const float* __restrict__ W_mem,
    const int* __restrict__ offs, const int* __restrict__ indeg,
    const int* __restrict__ esrc, const float4* __restrict__ egeo,
    const float* __restrict__ ecode, const float* __restrict__ chi,
    const float* __restrict__ A, const float* __restrict__ W1,
    float* __restrict__ P2)
{
    __shared__ float Als[1080];
    __shared__ float Qls[1080];
    __shared__ float Wm[144];
    __shared__ float B2ls[324];
    const int n = blockIdx.x, lane = threadIdx.x;
    #pragma unroll
    for (int k = 0; k < 17; k++) {
        const int i = lane + 64 * k;
        if (i < 1080) Als[i] = A[(size_t)n*1080 + i];
    }
    Wm[lane] = W_mem[lane];
    Wm[lane + 64] = W_mem[lane + 64];
    if (lane < 16) Wm[lane + 128] = W_mem[lane + 128];
    int aslot[3], cslot[3], rslot[3];
    float acc[3][6];
    #pragma unroll
    for (int j = 0; j < 3; j++) {
        const int p = lane + 64 * j;
        const int pc = (p < 180) ? p : 0;
        aslot[j] = pc / 9;
        cslot[j] = 20 + pc % 9;
        rslot[j] = 29 + 6 * l_of_a(pc / 9);
        #pragma unroll
        for (int s = 0; s < 6; s++) acc[j][s] = 0.f;
    }
    float fr[6];
    #pragma unroll
    for (int q = 0; q < 6; q++) fr[q] = freqs[q];
    float wrtB[6], wrtA[6];
    if (lane >= 29 && lane < 53) {
        const int j = lane - 29, l = j / 6, s2 = j % 6;
        #pragma unroll
        for (int q = 0; q < 6; q++) {
            wrtB[q] = W_rt[(l*6 + q)*6 + s2];
            wrtA[q] = W_Ar[(l*6 + q)*6 + s2];
        }
    }
    int mlx = 0, mly = 0, mlz = 0;
    if (lane < 20) { mlx = c_mx[lane]; mly = c_my[lane]; mlz = c_mz[lane]; }
    __syncthreads();   // Als/Wm visible; loop below is barrier-free
    const int e0 = offs[n], cnt = indeg[n];
    int sn2 = 0;
    float4 geo = make_float4(0.f, 0.f, 0.f, 1.f);
    float ecd = 0.f, chin = 0.f;
    float an[3][6];
    #pragma unroll
    for (int j = 0; j < 3; j++)
        #pragma unroll
        for (int s = 0; s < 6; s++) an[j][s] = 0.f;
    if (cnt > 0) {
        const int sn1 = esrc[e0];
        geo = egeo[e0];
        if (lane >= 20 && lane < 29) {
            ecd  = ecode[(size_t)e0*9 + lane - 20];
            chin = chi[(size_t)sn1*9 + lane - 20];
        }
        const float* ar = A + (size_t)sn1 * 1080;
        #pragma unroll
        for (int j = 0; j < 3; j++)
            #pragma unroll
            for (int s = 0; s < 6; s++) an[j][s] = ar[s*180 + lane + 64*j];
    }
    if (cnt > 1) sn2 = esrc[e0 + 1];
    for (int t = 0; t < cnt; t++) {
        const float4 g = geo;
        const float ec = ecd, ch = chin;
        float av[3][6];
        #pragma unroll
        for (int j = 0; j < 3; j++)
            #pragma unroll
            for (int s = 0; s < 6; s++) av[j][s] = an[j][s];
        if (t + 1 < cnt) {
            geo = egeo[e0 + t + 1];
            if (lane >= 20 && lane < 29) {
                ecd  = ecode[(size_t)(e0 + t + 1)*9 + lane - 20];
                chin = chi[(size_t)sn2*9 + lane - 20];
            }
            const float* ar = A + (size_t)sn2 * 1080;
            #pragma unroll
            for (int j = 0; j < 3; j++)
                #pragma unroll
                for (int s = 0; s < 6; s++) an[j][s] = ar[s*180 + lane + 64*j];
            if (t + 2 < cnt) sn2 = esrc[e0 + t + 2];
        }
        float regX = ec * ch;
        float regY = 0.f;
        if (lane < 20) {
            float v = 1.f;
            for (int i = 0; i < mlx; i++) v *= g.x;
            for (int i = 0; i < mly; i++) v *= g.y;
            for (int i = 0; i < mlz; i++) v *= g.z;
            regX = v;
        } else if (lane >= 29 && lane < 53) {
            const float r = g.w;
            const float u = r * (1.0f / 5.5f);
            const float u2 = u*u, u3 = u2*u, u6 = u3*u3;
            const float fcv = 1.0f - 28.0f*u6 + 48.0f*u6*u - 21.0f*u6*u2;
            const float inv = fcv / r;
            float sB = 0.f, sA = 0.f;
            #pragma unroll
            for (int q = 0; q < 6; q++) {
                const float rb = RBF_NORM * __sinf(r * fr[q]) * inv;
                sB = fmaf(rb, wrtB[q], sB);
                sA = fmaf(rb, wrtA[q], sA);
            }
            regX = sB;
            regY = sA;
        }
        float pp[3];
        #pragma unroll
        for (int j = 0; j < 3; j++)
            pp[j] = __shfl(regX, aslot[j]) * __shfl(regX, cslot[j]);
        #pragma unroll
        for (int j = 0; j < 3; j++) {
            #pragma unroll
            for (int s = 0; s < 6; s++) {
                const float rB = __shfl(regX, rslot[j] + s);
                const float rA = __shfl(regY, rslot[j] + s);
                acc[j][s] += rB * pp[j] + av[j][s] * rA;
            }
        }
    }
    // memory term + MP_NORM -> Qls (Als reads hoisted per pair)
    #pragma unroll
    for (int j = 0; j < 3; j++) {
        const int p = lane + 64 * j;
        if (p < 180) {
            const int l = l_of_a(p / 9);
            float als6[6];
            #pragma unroll
            for (int sp = 0; sp < 6; sp++) als6[sp] = Als[sp*180 + p];
            #pragma unroll
            for (int s = 0; s < 6; s++) {
                float m = 0.f;
                #pragma unroll
                for (int sp = 0; sp < 6; sp++)
                    m = fmaf(als6[sp], Wm[l*36 + sp*6 + s], m);
                Qls[s*180 + p] = acc[j][s] * MP_NORM + m;
            }
        }
    }
    __syncthreads();
    symm_from_lds(Qls, B2ls, lane);
    __syncthreads();
    // pipelined GEMV vs odd W1 rows
    {
        float cur[6], nxt[6];
        #pragma unroll
        for (int u = 0; u < 6; u++) cur[u] = W1[(size_t)(2*u + 1)*64 + lane];
        float s0=0.f, s1=0.f, s2=0.f, s3=0.f, s4=0.f, s5=0.f;
        for (int q = 0; q < 324; q += 6) {
            const int qn = q + 6;
            if (qn < 324) {
                #pragma unroll
                for (int u = 0; u < 6; u++)
                    nxt[u] = W1[(size_t)(2*(qn+u) + 1)*64 + lane];
            }
            s0 = fmaf(B2ls[q+0], cur[0], s0);
            s1 = fmaf(B2ls[q+1], cur[1], s1);
            s2 = fmaf(B2ls[q+2], cur[2], s2);
            s3 = fmaf(B2ls[q+3], cur[3], s3);
            s4 = fmaf(B2ls[q+4], cur[4], s4);
            s5 = fmaf(B2ls[q+5], cur[5], s5);
            #pragma unroll
            for (int u = 0; u < 6; u++) cur[u] = nxt[u];
        }
        P2[(size_t)n*64 + lane] = ((s0 + s1) + (s2 + s3)) + (s4 + s5);
    }
}

// ---------------------------------------------------------------------------
// Tail: 64 nodes per 256-thread block; LDS atomics only; block partials.
// ---------------------------------------------------------------------------
__global__ __launch_bounds__(256) void k_tail(
    const float* __restrict__ P1, const float* __restrict__ P2,
    const float* __restrict__ b1, const float* __restrict__ W2,
    const float* __restrict__ b2, const float* __restrict__ W3,
    const float* __restrict__ b3, const int* __restrict__ batch,
    float* __restrict__ part)
{
    __shared__ float h1s[64][66];
    __shared__ float W2L[2048];
    __shared__ float gsum[16];
    const int tid = threadIdx.x;
    const int nb = blockIdx.x * 64;
    if (tid < 16) gsum[tid] = 0.f;
    for (int idx = tid; idx < 2048; idx += 256) W2L[idx] = W2[idx];
    for (int idx = tid; idx < 4096; idx += 256) {
        const int nl = idx >> 6, o = idx & 63;
        float h = 0.f;
        if (nb + nl < NN)
            h = P1[(size_t)(nb + nl)*64 + o] + P2[(size_t)(nb + nl)*64 + o]
              + b1[o];
        h1s[nl][o] = h / (1.f + __expf(-h));
    }
    __syncthreads();
    const int nl = tid >> 2, og = (tid & 3) * 8;
    float acc2[8];
    #pragma unroll
    for (int j = 0; j < 8; j++) acc2[j] = b2[og + j];
    #pragma unroll 8
    for (int k = 0; k < 64; k++) {
        const float hv = h1s[nl][k];
        const float4 wA = *(const float4*)&W2L[k*32 + og];
        const float4 wB = *(const float4*)&W2L[k*32 + og + 4];
        acc2[0] = fmaf(hv, wA.x, acc2[0]); acc2[1] = fmaf(hv, wA.y, acc2[1]);
        acc2[2] = fmaf(hv, wA.z, acc2[2]); acc2[3] = fmaf(hv, wA.w, acc2[3]);
        acc2[4] = fmaf(hv, wB.x, acc2[4]); acc2[5] = fmaf(hv, wB.y, acc2[5]);
        acc2[6] = fmaf(hv, wB.z, acc2[6]); acc2[7] = fmaf(hv, wB.w, acc2[7]);
    }
    float s = 0.f;
    #pragma unroll
    for (int j = 0; j < 8; j++) {
        const float g = acc2[j] / (1.f + __expf(-acc2[j]));
        s = fmaf(g, W3[og + j], s);
    }
    s += __shfl_xor(s, 1);
    s += __shfl_xor(s, 2);
    if ((tid & 3) == 0 && nb + nl < NN)
        atomicAdd(&gsum[batch[nb + nl]], s + b3[0]);
    __syncthreads();
    if (tid < 16) part[blockIdx.x * 16 + tid] = gsum[tid];
}

__global__ __launch_bounds__(64) void k_final(const float* __restrict__ part,
                                              float* __restrict__ out)
{
    const int t = threadIdx.x;
    if (t >= 16) return;
    float acc = 0.f;
    for (int b = 0; b < NBLK; b++) acc += part[b * 16 + t];
    out[t] = acc;
}

extern "C" void kernel_launch(void* const* d_in, const int* in_sizes, int n_in,
                              void* d_out, int out_size, void* d_ws, size_t ws_size,
                              hipStream_t stream)
{
    const float* pos    = (const float*)d_in[0];
    const int*   ntype  = (const int*)  d_in[1];
    const int*   src    = (const int*)  d_in[2];
    const int*   dst    = (const int*)  d_in[3];
    const float* shifts = (const float*)d_in[4];
    const int*   batch  = (const int*)  d_in[5];
    const float* Wemb   = (const float*)d_in[6];
    const float* freqs  = (const float*)d_in[7];
    const float* W_rt   = (const float*)d_in[8];
    const float* W_mem  = (const float*)d_in[9];
    const float* W_Ar   = (const float*)d_in[10];
    const float* W_chi  = (const float*)d_in[11];
    const float* W1     = (const float*)d_in[12];
    const float* b1     = (const float*)d_in[13];
    const float* W2     = (const float*)d_in[14];
    const float* b2     = (const float*)d_in[15];
    const float* W3     = (const float*)d_in[16];
    const float* b3     = (const float*)d_in[17];

    float*  ws    = (float*)d_ws;
    float*  A     = ws;                        // [NN,1080]
    float*  P1    = A    + (size_t)NN * 1080;  // [NN,64]
    float*  P2    = P1   + (size_t)NN * 64;    // [NN,64]
    float*  chi   = P2   + (size_t)NN * 64;    // [NN,9]
    float4* egeo  = (float4*)(chi + (size_t)NN * 9);       // [NE]
    int*    esrc  = (int*)(egeo + NE);                     // [NE]
    float*  ecode = (float*)(esrc + NE);                   // [NE,9]
    float*  part  = ecode + (size_t)NE * 9;                // [NBLK,16]
    int*    indeg  = (int*)(part + NBLK * 16);
    int*    offs   = indeg  + 10240;
    int*    cursor = offs   + 10240;

    hipMemsetAsync(indeg,  0, 10240 * sizeof(int), stream);
    hipMemsetAsync(cursor, 0, 10240 * sizeof(int), stream);

    k_hist<<<(NE + 255)/256, 256, 0, stream>>>(pos, src, dst, shifts, indeg);
    k_scan<<<1, 256, 0, stream>>>(indeg, offs);
    k_fill<<<(NE + 255)/256, 256, 0, stream>>>(pos, src, dst, shifts, ntype,
                                               Wemb, offs, cursor, esrc, egeo,
                                               ecode);
    k_node1<<<NN, 64, 0, stream>>>(freqs, W_rt, offs, indeg, esrc, egeo, ecode,
                                   W1, W_chi, A, chi, P1);
    k_node2<<<NN, 64, 0, stream>>>(freqs, W_rt, W_Ar, W_mem, offs, indeg, esrc,
                                   egeo, ecode, chi, A, W1, P2);
    k_tail<<<NBLK, 256, 0, stream>>>(P1, P2, b1, W2, b2, W3, b3, batch, part);
    k_final<<<1, 64, 0, stream>>>(part, (float*)d_out);
}